// Round 10
// baseline (575.345 us; speedup 1.0000x reference)
//
#include <hip/hip_runtime.h>
#include <hip/hip_cooperative_groups.h>
#include <cstdint>
#include <cstddef>

// ---------------------------------------------------------------------------
// AtomicRouteConv, sort-based CSR + fp16 MFMA pipeline.
//   R1: scatter occupancy fix (SP_CHUNK 2048, one chunk/list per block).
//   R2: MFMA QK^T in attn -> REGRESSED (latency-bound). Reverted.
//   R3: 16-edge tiles + fdot2 in attn; pull1 16-wide.
//   R4/R5: algebraic K/V elimination; U stored locally-normalized (f16-safe).
//   R6: GEMM weight LDS staging (XOR-swizzled) -> stage1 45->~10us. 344us.
//   R7: CRASHED -> fused dual-path s1qp kernel (dropped for good).
//   R8: atomic-S to ONE float REGRESSED attn 30->165us (single-cache-line
//   serialization). R9: contention-free partial[]+reduce. 325.8us; top-5 all
//   harness fills -> ~150us of the residual is 12 launch gaps (~12us each).
//   R10: launch-count reduction 12 -> 6.
//     (a) ONE cooperative kernel (grid.sync phases) = memset+setup+hist+
//         scan+scatter+sort. Phase bodies identical to proven kernels,
//         grid-strided over 512 blocks (co-residency safe; no early returns).
//     (b) reduce_partials deleted: attn atomicAdds into 64 PADDED slots
//         (~195 adds/line, lines parallel -> no R8 serialization);
//         gemm_v sums the 64 slots with one 64-lane shuffle reduce.
//   CSR1 (by mid): s[m] = sum x_src rows (f16 gather, f32 acc), deg[m]
//   h = deg*(x_mid@W1^T + b12) + s@W2^T      (MFMA; x_mid read f32)
//   Q' = x_dst@(q_w^T k_w)+q_b k_w (prefused); qc = x_dst.wqkb + qb.kb
//   CSR2 (by dst), one wave per dst: U^ = sum(a*h)/sum(a), sexp = f*sum(a)
//   out = sexp/S * (U^@v_w^T + v_b)
// NOTE: bucket = key>>8 requires N <= 65536 (here N=50000).
// ---------------------------------------------------------------------------

namespace cg = cooperative_groups;

using f16   = _Float16;
using f16x2 = __attribute__((ext_vector_type(2))) _Float16;
using f16x4 = __attribute__((ext_vector_type(4))) _Float16;
using f16x8 = __attribute__((ext_vector_type(8))) _Float16;
using f32x4 = __attribute__((ext_vector_type(4))) float;

#define SP_CHUNK 2048
#define CSR_BLOCKS 512

// LDS swizzle on 16B-vector index: XOR row&7 (row = vec>>4) into bits [0:2].
// B-fragment read (r16 strided 256B) 16-way -> 2-way bank conflict (free).
__device__ __forceinline__ int swzv(int v) { return v ^ ((v >> 4) & 7); }

// ---- cooperative setup + CSR build ----------------------------------------
struct CsrArgs {
    const float *W1, *W2, *vw, *b1, *b2, *qw, *kw, *qb, *kb, *xsrc;
    f16 *wh; float *b12, *bqk, *wqkb, *cconst; f16 *xs_h; int na4;
    const int *ei1; int E1, nb1; int *ch1p, *cur1p, *cb1;
    const int *ei2; int E2, nb2; int *ch2p, *cur2p, *cb2;
    int2 *p1, *p2; int *off1, *lst1, *off2, *lstm2;
    int N1, N2, nch1, nch2;
    float *slots;   // 64 slots, padded *16 floats (64B lines)
};

__global__ __launch_bounds__(256) void coop_csr(CsrArgs a)
{
    cg::grid_group grid = cg::this_grid();
    __shared__ int sh[512];
    __shared__ int sh2[256];
    const int tid = threadIdx.x;
    const int gsz = gridDim.x * 256;
    const int g0  = blockIdx.x * 256 + tid;

    // ---- phase A: setup (weights cvt + b12 + prefused qk + x_src cvt)
    //      + zero coarse counters + zero S-slots ----
    {
        int totalA = 4 * 16384 + 257 + a.na4;
        for (int idx = g0; idx < totalA; idx += gsz) {
            if (idx < 3 * 16384) {
                const float* src = (idx < 16384) ? a.W1 :
                                   (idx < 2 * 16384) ? a.W2 : a.vw;
                a.wh[idx] = (f16)src[idx & 16383];
            } else if (idx < 3 * 16384 + 128) {
                int j = idx - 3 * 16384;
                a.b12[j] = a.b1[j] + a.b2[j];
            } else if (idx < 4 * 16384 + 128) {
                int e = idx - (3 * 16384 + 128);
                int col = e >> 7, i = e & 127;
                float s = 0.f;
                for (int j = 0; j < 128; ++j)
                    s += a.qw[j * 128 + i] * a.kw[j * 128 + col];
                a.wh[3 * 16384 + col * 128 + i] = (f16)s;
            } else if (idx < 4 * 16384 + 256) {
                int t = idx - (4 * 16384 + 128);
                float s1 = 0.f, s2 = 0.f;
                for (int j = 0; j < 128; ++j) {
                    s1 += a.qw[j * 128 + t] * a.kb[j];
                    s2 += a.qb[j] * a.kw[j * 128 + t];
                }
                a.wqkb[t] = s1;
                a.bqk[t] = s2;
            } else if (idx == 4 * 16384 + 256) {
                float s3 = 0.f;
                for (int j = 0; j < 128; ++j) s3 += a.qb[j] * a.kb[j];
                a.cconst[0] = s3;
            } else {
                int j = idx - (4 * 16384 + 257);
                if (j < a.na4) {
                    float4 v = ((const float4*)a.xsrc)[j];
                    f16x4 o = {(f16)v.x, (f16)v.y, (f16)v.z, (f16)v.w};
                    ((f16x4*)a.xs_h)[j] = o;
                }
            }
        }
        int nz = (a.nb1 + a.nb2) * 16;           // ch1p|ch2p contiguous
        for (int i = g0; i < nz; i += gsz) a.ch1p[i] = 0;
        for (int i = g0; i < 64 * 16; i += gsz) a.slots[i] = 0.f;
    }
    grid.sync();

    // ---- phase B: coarse histogram (LDS-aggregated) ----
    {
        for (int i = tid; i < a.nb1 + a.nb2; i += 256) sh[i] = 0;
        __syncthreads();
        for (int e = g0; e < a.E1; e += gsz)
            atomicAdd(&sh[a.ei1[a.E1 + e] >> 8], 1);
        for (int e = g0; e < a.E2; e += gsz)
            atomicAdd(&sh[a.nb1 + (a.ei2[a.E2 + e] >> 8)], 1);
        __syncthreads();
        for (int i = tid; i < a.nb1; i += 256) { int c = sh[i];         if (c) atomicAdd(&a.ch1p[i * 16], c); }
        for (int i = tid; i < a.nb2; i += 256) { int c = sh[a.nb1 + i]; if (c) atomicAdd(&a.ch2p[i * 16], c); }
    }
    grid.sync();

    // ---- phase C: scan coarse buckets -> bases + cursors (block 0) ----
    if (blockIdx.x == 0) {
        int v = (tid < a.nb1) ? a.ch1p[tid * 16] : 0;
        sh[tid] = v; __syncthreads();
        for (int d = 1; d < 256; d <<= 1) {
            int t = (tid >= d) ? sh[tid - d] : 0;
            __syncthreads(); sh[tid] += t; __syncthreads();
        }
        if (tid < a.nb1) { int ex = sh[tid] - v; a.cb1[tid] = ex; a.cur1p[tid * 16] = ex; }
        if (tid == 0) a.cb1[a.nb1] = a.E1;
        __syncthreads();
        int v2 = (tid < a.nb2) ? a.ch2p[tid * 16] : 0;
        sh[tid] = v2; __syncthreads();
        for (int d = 1; d < 256; d <<= 1) {
            int t = (tid >= d) ? sh[tid - d] : 0;
            __syncthreads(); sh[tid] += t; __syncthreads();
        }
        if (tid < a.nb2) { int ex = sh[tid] - v2; a.cb2[tid] = ex; a.cur2p[tid * 16] = ex; }
        if (tid == 0) a.cb2[a.nb2] = a.E2;
    }
    grid.sync();

    // ---- phase D: block-chunked pair scatter ----
    for (int c = blockIdx.x; c < a.nch1 + a.nch2; c += gridDim.x) {
        __syncthreads();   // protect LDS reuse across iterations
        const int* keys; const int* pay; int E; int* curp; int2* out; int nbk; int chunk;
        if (c < a.nch1) { keys = a.ei1 + a.E1; pay = a.ei1; E = a.E1; curp = a.cur1p; out = a.p1; nbk = a.nb1; chunk = c; }
        else            { keys = a.ei2 + a.E2; pay = a.ei2; E = a.E2; curp = a.cur2p; out = a.p2; nbk = a.nb2; chunk = c - a.nch1; }
        int start = chunk * SP_CHUNK;
        int end = start + SP_CHUNK; if (end > E) end = E;

        for (int i = tid; i < nbk; i += 256) sh[i] = 0;
        __syncthreads();
        for (int i = start + tid; i < end; i += 256)
            atomicAdd(&sh[keys[i] >> 8], 1);
        __syncthreads();
        for (int i = tid; i < nbk; i += 256) {
            int cc = sh[i];
            sh2[i] = cc ? atomicAdd(&curp[i * 16], cc) : 0;
            sh[i] = 0;   // reuse as local cursor
        }
        __syncthreads();
        for (int i = start + tid; i < end; i += 256) {
            int key = keys[i];
            int b = key >> 8;
            int lp = atomicAdd(&sh[b], 1);
            out[sh2[b] + lp] = make_int2(key, pay[i]);
        }
    }
    grid.sync();

    // ---- phase E: per-bucket counting sort -> off[] + payload[] ----
    for (int kb0 = blockIdx.x; kb0 < a.nb1 + a.nb2; kb0 += gridDim.x) {
        __syncthreads();   // protect LDS reuse across iterations
        int kb = kb0;
        const int2* pairs; const int* cb; int N, E; int* offk; int* outp;
        if (kb < a.nb1) { pairs = a.p1; cb = a.cb1; N = a.N1; E = a.E1; offk = a.off1; outp = a.lst1; }
        else { kb -= a.nb1; pairs = a.p2; cb = a.cb2; N = a.N2; E = a.E2; offk = a.off2; outp = a.lstm2; }
        int base = cb[kb], cnt = cb[kb + 1] - base;
        int key0 = kb << 8;
        int nk = N - key0; if (nk > 256) nk = 256;

        sh[tid] = 0;
        __syncthreads();
        for (int i = tid; i < cnt; i += 256)
            atomicAdd(&sh[pairs[base + i].x - key0], 1);
        __syncthreads();
        int v = sh[tid];
        sh2[tid] = v; __syncthreads();
        for (int d = 1; d < 256; d <<= 1) {
            int t = (tid >= d) ? sh2[tid - d] : 0;
            __syncthreads(); sh2[tid] += t; __syncthreads();
        }
        int ex = sh2[tid] - v;
        if (tid < nk) offk[key0 + tid] = base + ex;
        if (tid == 0 && key0 + nk == N) offk[N] = E;
        sh[tid] = ex;   // reuse as per-key cursor
        __syncthreads();
        for (int i = tid; i < cnt; i += 256) {
            int2 pr = pairs[base + i];
            int p = atomicAdd(&sh[pr.x - key0], 1);
            outp[base + p] = pr.y;
        }
    }
}

// ---- pull1: s[m] = sum of fp16 x_src rows; deg[m] -------------------------
__global__ __launch_bounds__(256) void pull1_h(
    const f16* __restrict__ xs, const int* __restrict__ off,
    const int* __restrict__ lst, f16* __restrict__ s,
    float* __restrict__ deg, int N)
{
    int w = blockIdx.x * 4 + (threadIdx.x >> 6);
    int l = threadIdx.x & 63;
    if (w >= N) return;
    int b = off[w], e = off[w + 1];
    float ax = 0.f, ay = 0.f;
    for (int i = b; i < e; i += 16) {
        int idx[16];
        f16x2 a[16];
#pragma unroll
        for (int u = 0; u < 16; ++u) {
            int id = i + u;
            idx[u] = lst[(id < e) ? id : b];
        }
#pragma unroll
        for (int u = 0; u < 16; ++u)
            a[u] = *(const f16x2*)(xs + (size_t)idx[u] * 128 + l * 2);
#pragma unroll
        for (int u = 0; u < 16; ++u) {
            bool val = (i + u) < e;
            ax += val ? (float)a[u][0] : 0.f;
            ay += val ? (float)a[u][1] : 0.f;
        }
    }
    f16x2 o = {(f16)ax, (f16)ay};
    *(f16x2*)(s + (size_t)w * 128 + l * 2) = o;
    if (l == 0) deg[w] = (float)(e - b);
}

// ---- MFMA stage1: H = deg*(Xm@W1^T + b12) + S@W2^T ------------------------
__global__ __launch_bounds__(256) void gemm_stage1_mfma(
    const float* __restrict__ Xm, const f16* __restrict__ S,
    const f16* __restrict__ w12, const float* __restrict__ b12,
    const float* __restrict__ deg, f16* __restrict__ H, int M)
{
    __shared__ f16 lw[32768];   // w1 rows 0-127, w2 rows 128-255 (swizzled)
    int tid = threadIdx.x;
    int lane = tid & 63;
    int r16 = lane & 15, quad = lane >> 4;
    int gw = (blockIdx.x * 256 + tid) >> 6;
    int mb = gw * 16;
    bool active = mb < M;
    int row = mb + r16; if (row >= M) row = M - 1;

    f32x4 alo[4], ahi[4];
    f16x8 a2[4];
    if (active) {
        const float* xa = Xm + (size_t)row * 128 + quad * 8;
        const f16* xb = S + (size_t)row * 128 + quad * 8;
#pragma unroll
        for (int kb = 0; kb < 4; ++kb) {
            alo[kb] = *(const f32x4*)(xa + kb * 32);
            ahi[kb] = *(const f32x4*)(xa + kb * 32 + 4);
            a2[kb] = *(const f16x8*)(xb + kb * 32);
        }
    }
    {
        const f16x8* gsrc = (const f16x8*)w12;   // 4096 16B vectors
        f16x8* ldst = (f16x8*)lw;
#pragma unroll
        for (int u = 0; u < 16; ++u) {
            int i = u * 256 + tid;
            ldst[swzv(i)] = gsrc[i];
        }
    }
    __syncthreads();
    if (!active) return;

    f16x8 a1[4];
#pragma unroll
    for (int kb = 0; kb < 4; ++kb)
#pragma unroll
        for (int j = 0; j < 4; ++j) {
            a1[kb][j] = (f16)alo[kb][j];
            a1[kb][4 + j] = (f16)ahi[kb][j];
        }

    f32x4 accA[8], accB[8];
#pragma unroll
    for (int t = 0; t < 8; ++t) {
        accA[t] = (f32x4){0.f, 0.f, 0.f, 0.f};
        accB[t] = (f32x4){0.f, 0.f, 0.f, 0.f};
    }
    const f16x8* lv = (const f16x8*)lw;
#pragma unroll
    for (int kb = 0; kb < 4; ++kb) {
#pragma unroll
        for (int t = 0; t < 8; ++t) {
            int r = t * 16 + r16;
            f16x8 bw1 = lv[swzv(r * 16 + kb * 4 + quad)];
            f16x8 bw2 = lv[swzv((r + 128) * 16 + kb * 4 + quad)];
            accA[t] = __builtin_amdgcn_mfma_f32_16x16x32_f16(a1[kb], bw1, accA[t], 0, 0, 0);
            accB[t] = __builtin_amdgcn_mfma_f32_16x16x32_f16(a2[kb], bw2, accB[t], 0, 0, 0);
        }
    }
    float dv[4];
#pragma unroll
    for (int i = 0; i < 4; ++i) {
        int r = mb + quad * 4 + i;
        dv[i] = (r < M) ? deg[r] : 0.f;
    }
#pragma unroll
    for (int t = 0; t < 8; ++t) {
        int col = t * 16 + r16;
        float bb = b12[col];
#pragma unroll
        for (int i = 0; i < 4; ++i) {
            int r = mb + quad * 4 + i;
            if (r < M)
                H[(size_t)r * 128 + col] = (f16)(dv[i] * (accA[t][i] + bb) + accB[t][i]);
        }
    }
}

// ---- MFMA Q': Qp = Xd@wqk'^T + bqk; qc = Xd.wqkb + cconst (Xd f32) --------
__global__ __launch_bounds__(256) void gemm_qp_mfma(
    const float* __restrict__ Xd, const f16* __restrict__ W,
    const float* __restrict__ bias, const float* __restrict__ wqkb,
    const float* __restrict__ cconst, f16* __restrict__ Qp,
    float* __restrict__ qc, int M)
{
    __shared__ f16 lw[16384];
    int tid = threadIdx.x;
    int lane = tid & 63;
    int r16 = lane & 15, quad = lane >> 4;
    int gw = (blockIdx.x * 256 + tid) >> 6;
    int mb = gw * 16;
    bool active = mb < M;
    int row = mb + r16; if (row >= M) row = M - 1;

    f32x4 alo[4], ahi[4];
    if (active) {
        const float* xp = Xd + (size_t)row * 128 + quad * 8;
#pragma unroll
        for (int kb = 0; kb < 4; ++kb) {
            alo[kb] = *(const f32x4*)(xp + kb * 32);
            ahi[kb] = *(const f32x4*)(xp + kb * 32 + 4);
        }
    }
    {
        const f16x8* gsrc = (const f16x8*)W;   // 2048 vectors
        f16x8* ldst = (f16x8*)lw;
#pragma unroll
        for (int u = 0; u < 8; ++u) {
            int i = u * 256 + tid;
            ldst[swzv(i)] = gsrc[i];
        }
    }
    __syncthreads();
    if (!active) return;

    f16x8 a[4];
    float pq = 0.f;
#pragma unroll
    for (int kb = 0; kb < 4; ++kb)
#pragma unroll
        for (int j = 0; j < 4; ++j) {
            a[kb][j] = (f16)alo[kb][j];
            a[kb][4 + j] = (f16)ahi[kb][j];
            pq += alo[kb][j] * wqkb[kb * 32 + quad * 8 + j];
            pq += ahi[kb][j] * wqkb[kb * 32 + quad * 8 + 4 + j];
        }

    f32x4 acc[8];
#pragma unroll
    for (int t = 0; t < 8; ++t) acc[t] = (f32x4){0.f, 0.f, 0.f, 0.f};
    const f16x8* lv = (const f16x8*)lw;
#pragma unroll
    for (int kb = 0; kb < 4; ++kb) {
#pragma unroll
        for (int t = 0; t < 8; ++t) {
            f16x8 b = lv[swzv((t * 16 + r16) * 16 + kb * 4 + quad)];
            acc[t] = __builtin_amdgcn_mfma_f32_16x16x32_f16(a[kb], b, acc[t], 0, 0, 0);
        }
    }
    pq += __shfl_xor(pq, 16);
    pq += __shfl_xor(pq, 32);
    if (quad == 0 && mb + r16 < M) qc[mb + r16] = pq + cconst[0];
#pragma unroll
    for (int t = 0; t < 8; ++t) {
        int col = t * 16 + r16;
        float bv = bias[col];
#pragma unroll
        for (int i = 0; i < 4; ++i) {
            int r = mb + quad * 4 + i;
            if (r < M) Qp[(size_t)r * 128 + col] = (f16)(acc[t][i] + bv);
        }
    }
}

// ---- MFMA V: out = (U^@wv^T + vb) * sexp/S; S = sum of 64 slots -----------
__global__ __launch_bounds__(256) void gemm_v_mfma(
    const f16* U, const f16* __restrict__ W,
    const float* __restrict__ vb, const float* __restrict__ sexp,
    const float* __restrict__ slots, float* __restrict__ out, int M)
{
    __shared__ f16 lw[16384];
    int tid = threadIdx.x;
    int lane = tid & 63;
    int r16 = lane & 15, quad = lane >> 4;
    int gw = (blockIdx.x * 256 + tid) >> 6;
    int mb = gw * 16;
    bool active = mb < M;
    int row = mb + r16; if (row >= M) row = M - 1;

    f16x8 a[4];
    if (active) {
        const f16* xp = U + (size_t)row * 128 + quad * 8;
#pragma unroll
        for (int kb = 0; kb < 4; ++kb)
            a[kb] = *(const f16x8*)(xp + kb * 32);
    }
    {
        const f16x8* gsrc = (const f16x8*)W;
        f16x8* ldst = (f16x8*)lw;
#pragma unroll
        for (int u = 0; u < 8; ++u) {
            int i = u * 256 + tid;
            ldst[swzv(i)] = gsrc[i];
        }
    }
    // S = sum of the 64 padded slots (one per lane, 64-lane shuffle reduce)
    float sv_ = slots[lane * 16];
#pragma unroll
    for (int o = 1; o < 64; o <<= 1) sv_ += __shfl_xor(sv_, o);
    float invS = 1.0f / sv_;

    __syncthreads();
    if (!active) return;

    f32x4 acc[8];
#pragma unroll
    for (int t = 0; t < 8; ++t) acc[t] = (f32x4){0.f, 0.f, 0.f, 0.f};

    const f16x8* lv = (const f16x8*)lw;
#pragma unroll
    for (int kb = 0; kb < 4; ++kb) {
#pragma unroll
        for (int t = 0; t < 8; ++t) {
            f16x8 b = lv[swzv((t * 16 + r16) * 16 + kb * 4 + quad)];
            acc[t] = __builtin_amdgcn_mfma_f32_16x16x32_f16(a[kb], b, acc[t], 0, 0, 0);
        }
    }
    float sv[4];
#pragma unroll
    for (int i = 0; i < 4; ++i) {
        int r = mb + quad * 4 + i;
        sv[i] = (r < M) ? sexp[r] * invS : 0.f;
    }
#pragma unroll
    for (int t = 0; t < 8; ++t) {
        int col = t * 16 + r16;
        float bv = vb[col];
#pragma unroll
        for (int i = 0; i < 4; ++i) {
            int r = mb + quad * 4 + i;
            if (r < M)
                out[(size_t)r * 128 + col] = (acc[t][i] + bv) * sv[i];
        }
    }
}

// ---- fused attention: one wave per dst, h-only gather; 64-slot S ----------
__global__ __launch_bounds__(256) void attn_fused_h(
    const f16* __restrict__ Qp, const f16* __restrict__ H,
    const float* __restrict__ qc, const int* __restrict__ off,
    const int* __restrict__ lstm, f16* __restrict__ U,
    float* __restrict__ sexp, float* __restrict__ slots, int N)
{
    const int tid  = threadIdx.x;
    const int w    = blockIdx.x * 4 + (tid >> 6);
    const int lane = tid & 63;
    const int sub  = lane >> 4;
    const int c    = lane & 15;
    const float scale = 0.08838834764831845f;  // 1/sqrt(128)

    float acc[8];
#pragma unroll
    for (int j = 0; j < 8; ++j) acc[j] = 0.f;
    float ssum = 0.f;
    float factor = 0.f;

    if (w < N) {
        factor = __expf(qc[w] * scale);
        int b = off[w], e = off[w + 1];
        if (b < e) {
            f16x8 qh = *(const f16x8*)(Qp + (size_t)w * 128 + c * 8);
            f16x2 q2[4];
#pragma unroll
            for (int j = 0; j < 4; ++j) q2[j] = ((const f16x2*)&qh)[j];
            for (int i = b; i < e; i += 16) {
                int m[4]; bool val[4];
#pragma unroll
                for (int u = 0; u < 4; ++u) {
                    int id = i + sub * 4 + u;
                    val[u] = id < e;
                    m[u] = lstm[val[u] ? id : b];
                }
                f16x8 hh[4];
#pragma unroll
                for (int u = 0; u < 4; ++u)
                    hh[u] = *(const f16x8*)(H + (size_t)m[u] * 128 + c * 8);
                float p[4];
#pragma unroll
                for (int u = 0; u < 4; ++u) {
                    float s = 0.f;
                    const f16x2* h2 = (const f16x2*)&hh[u];
#pragma unroll
                    for (int j = 0; j < 4; ++j)
#if __has_builtin(__builtin_amdgcn_fdot2)
                        s = __builtin_amdgcn_fdot2(q2[j], h2[j], s, false);
#else
                        s += (float)q2[j][0] * (float)h2[j][0]
                           + (float)q2[j][1] * (float)h2[j][1];
#endif
                    p[u] = s;
                }
#pragma unroll
                for (int o = 1; o < 16; o <<= 1) {
#pragma unroll
                    for (int u = 0; u < 4; ++u)
                        p[u] += __shfl_xor(p[u], o);
                }
                float a[4];
#pragma unroll
                for (int u = 0; u < 4; ++u)
                    a[u] = val[u] ? __expf(p[u] * scale) : 0.f;
                ssum += (a[0] + a[1]) + (a[2] + a[3]);
#pragma unroll
                for (int u = 0; u < 4; ++u)
#pragma unroll
                    for (int j = 0; j < 8; ++j)
                        acc[j] += a[u] * (float)hh[u][j];
            }
        }
    }
    float stot = ssum;
    stot += __shfl_xor(stot, 16);
    stot += __shfl_xor(stot, 32);

    if (w < N) {
#pragma unroll
        for (int j = 0; j < 8; ++j) {
            acc[j] += __shfl_xor(acc[j], 16);
            acc[j] += __shfl_xor(acc[j], 32);
        }
        if (sub == 0) {
            float inv = (stot > 0.f) ? 1.0f / stot : 0.f;
            f16x8 o;
#pragma unroll
            for (int j = 0; j < 8; ++j) o[j] = (f16)(acc[j] * inv);
            *(f16x8*)(U + (size_t)w * 128 + c * 8) = o;
        }
    }
    float sg = stot * factor;   // 0 for w>=N
    if (lane == 0 && w < N) sexp[w] = sg;
    __shared__ float bs[4];
    if (lane == 0) bs[tid >> 6] = sg;
    __syncthreads();
    if (tid == 0) {
        float t = bs[0] + bs[1] + bs[2] + bs[3];
        if (t != 0.f) atomicAdd(&slots[(blockIdx.x & 63) * 16], t);
    }
}

// ---------------------------------------------------------------------------
extern "C" void kernel_launch(void* const* d_in, const int* in_sizes, int n_in,
                              void* d_out, int out_size, void* d_ws, size_t ws_size,
                              hipStream_t stream)
{
    const float* x_src = (const float*)d_in[0];
    const float* x_mid = (const float*)d_in[1];
    const float* x_dst = (const float*)d_in[2];
    const int*   ei1   = (const int*)d_in[3];
    const int*   ei2   = (const int*)d_in[4];
    const float* W1_w  = (const float*)d_in[5];
    const float* W1_b  = (const float*)d_in[6];
    const float* W2_w  = (const float*)d_in[7];
    const float* W2_b  = (const float*)d_in[8];
    const float* q_w   = (const float*)d_in[9];
    const float* q_b   = (const float*)d_in[10];
    const float* k_w   = (const float*)d_in[11];
    const float* k_b   = (const float*)d_in[12];
    const float* v_w   = (const float*)d_in[13];
    const float* v_b   = (const float*)d_in[14];

    const int NSRC = in_sizes[0] / 128;
    const int NMID = in_sizes[1] / 128;
    const int NDST = in_sizes[2] / 128;
    const int E1   = in_sizes[3] / 2;
    const int E2   = in_sizes[4] / 2;
    const int nb2g = (NDST + 3) / 4;               // attn grid
    const int nb1  = (NMID + 255) >> 8;            // coarse buckets
    const int nb2  = (NDST + 255) >> 8;

    auto al4 = [](size_t n) { return (n + 3) & ~(size_t)3; };

    // ---- workspace layout ----
    f16* xs_h = (f16*)d_ws;                        // NSRC*128
    f16* h_h  = xs_h + (size_t)NSRC * 128;         // NMID*128 (H)
    f16* s_h  = h_h + (size_t)NMID * 128;          // NMID*128
    f16* qp_h = s_h + (size_t)NMID * 128;          // NDST*128 (Q')
    f16* u_h  = qp_h + (size_t)NDST * 128;         // NDST*128 (U^)
    f16* w_h  = u_h + (size_t)NDST * 128;          // 4*16384
    f16* wvh = w_h + 2 * 16384;
    f16* wqk = w_h + 3 * 16384;

    float* b12 = (float*)(w_h + 4 * 16384);        // 128
    float* bqk = b12 + 128;                        // 128
    float* wqkb = bqk + 128;                       // 128
    float* cconst = wqkb + 128;                    // 4
    float* deg = cconst + 4;                       // NMID
    float* qcv = deg + al4(NMID);                  // NDST
    float* sexp = qcv + al4(NDST);                 // NDST
    float* slots = sexp + al4(NDST);               // 64*16 (padded S slots)

    int2* pairs1 = (int2*)(slots + 64 * 16);       // E1  (8B-aligned by layout)
    int2* pairs2 = pairs1 + E1;                    // E2
    int*  cb1   = (int*)(pairs2 + E2);             // nb1+1
    int*  cb2   = cb1 + al4(nb1 + 1);              // nb2+1
    int*  ch1p  = cb2 + al4(nb2 + 1);              // nb1*16 (zeroed in coop)
    int*  ch2p  = ch1p + nb1 * 16;                 // nb2*16
    int*  cur1p = ch2p + nb2 * 16;                 // nb1*16
    int*  cur2p = cur1p + nb1 * 16;                // nb2*16
    int*  off1  = cur2p + nb2 * 16;                // NMID+1
    int*  off2  = off1 + al4(NMID + 1);            // NDST+1
    int*  lst1  = off2 + al4(NDST + 1);            // E1 (src, grouped by mid)
    int*  lstm2 = lst1 + al4(E1);                  // E2 (mid, grouped by dst)

    // ---- fused cooperative setup + CSR build ----
    {
        CsrArgs ca;
        ca.W1 = W1_w; ca.W2 = W2_w; ca.vw = v_w; ca.b1 = W1_b; ca.b2 = W2_b;
        ca.qw = q_w; ca.kw = k_w; ca.qb = q_b; ca.kb = k_b; ca.xsrc = x_src;
        ca.wh = w_h; ca.b12 = b12; ca.bqk = bqk; ca.wqkb = wqkb;
        ca.cconst = cconst; ca.xs_h = xs_h; ca.na4 = NSRC * 32;
        ca.ei1 = ei1; ca.E1 = E1; ca.nb1 = nb1;
        ca.ch1p = ch1p; ca.cur1p = cur1p; ca.cb1 = cb1;
        ca.ei2 = ei2; ca.E2 = E2; ca.nb2 = nb2;
        ca.ch2p = ch2p; ca.cur2p = cur2p; ca.cb2 = cb2;
        ca.p1 = pairs1; ca.p2 = pairs2;
        ca.off1 = off1; ca.lst1 = lst1; ca.off2 = off2; ca.lstm2 = lstm2;
        ca.N1 = NMID; ca.N2 = NDST;
        ca.nch1 = (E1 + SP_CHUNK - 1) / SP_CHUNK;
        ca.nch2 = (E2 + SP_CHUNK - 1) / SP_CHUNK;
        ca.slots = slots;
        void* kp[] = {&ca};
        hipLaunchCooperativeKernel((void*)coop_csr, dim3(CSR_BLOCKS), dim3(256),
                                   kp, 0, stream);
    }

    // ---- stage 1 + Q' ----
    pull1_h<<<(NMID + 3) / 4, 256, 0, stream>>>(xs_h, off1, lst1, s_h, deg, NMID);

    int gbm = ((NMID + 15) / 16 + 3) / 4;
    int gbd = ((NDST + 15) / 16 + 3) / 4;
    gemm_stage1_mfma<<<gbm, 256, 0, stream>>>(x_mid, s_h, w_h /*w1|w2*/, b12,
                                              deg, h_h, NMID);
    gemm_qp_mfma<<<gbd, 256, 0, stream>>>(x_dst, wqk, bqk, wqkb, cconst,
                                          qp_h, qcv, NDST);

    // ---- fused attention (h-gather) + projection/normalize ----
    attn_fused_h<<<nb2g, 256, 0, stream>>>(qp_h, h_h, qcv, off2, lstm2,
                                           u_h, sexp, slots, NDST);
    gemm_v_mfma<<<gbd, 256, 0, stream>>>(u_h, wvh, v_b, sexp, slots,
                                         (float*)d_out, NDST);
}

// Round 11
// 338.244 us; speedup vs baseline: 1.7010x; 1.7010x over previous
//
#include <hip/hip_runtime.h>
#include <cstdint>
#include <cstddef>

// ---------------------------------------------------------------------------
// AtomicRouteConv, sort-based CSR + fp16 MFMA pipeline.
//   R1: scatter occupancy fix (SP_CHUNK 2048, one chunk/list per block).
//   R2: MFMA QK^T in attn -> REGRESSED (latency-bound). Reverted.
//   R3: 16-edge tiles + fdot2 in attn; pull1 16-wide.
//   R4/R5: algebraic K/V elimination; U stored locally-normalized (f16-safe).
//   R6: GEMM weight LDS staging (XOR-swizzled). 344us.
//   R7: CRASHED (fused dual-MFMA s1qp kernel; dropped).
//   R8: single-float atomic-S REGRESSED (one-cache-line serialization).
//   R9: contention-free partial[]+reduce; setup fusion; f32 A-reads. 325.8us.
//   R10: cooperative grid.sync CSR -> REGRESSED HARD (319us kernel, VALU
//   0.8%: grid.sync ~70us each on 8 non-coherent XCDs). Lesson: fuse only
//   INDEPENDENT work; never replace a launch gap with grid.sync.
//   R11: launch cuts 12 -> 8, all dependency-free fusions:
//     (a) memset deleted: hist WRITES 64 per-block partial histograms
//         (no zeroed counters needed); scan sums them.
//     (b) setup + hist fused (independent, disjoint block ranges).
//     (c) pull1 + qp fused (qp depends only on setup, not CSR).
//     (d) 64-padded-slot S (R10b): attn atomicAdds ~195x per line over 64
//         lines; gemm_v 64-lane slot reduce; reduce_partials deleted;
//         slots zeroed in scan.
//   CSR1 (by mid): s[m] = sum x_src rows (f16 gather, f32 acc), deg[m]
//   h = deg*(x_mid@W1^T + b12) + s@W2^T      (MFMA; x_mid read f32)
//   Q' = x_dst@(q_w^T k_w)+q_b k_w (prefused); qc = x_dst.wqkb + qb.kb
//   CSR2 (by dst), one wave per dst: U^ = sum(a*h)/sum(a), sexp = f*sum(a)
//   out = sexp/S * (U^@v_w^T + v_b)
// NOTE: bucket = key>>8 requires N <= 65536 (here N=50000).
// ---------------------------------------------------------------------------

using f16   = _Float16;
using f16x2 = __attribute__((ext_vector_type(2))) _Float16;
using f16x4 = __attribute__((ext_vector_type(4))) _Float16;
using f16x8 = __attribute__((ext_vector_type(8))) _Float16;
using f32x4 = __attribute__((ext_vector_type(4))) float;

#define SP_CHUNK 2048
#define NHIST 64

// LDS swizzle on 16B-vector index: XOR row&7 (row = vec>>4) into bits [0:2].
// B-fragment read (r16 strided 256B) 16-way -> 2-way bank conflict (free).
__device__ __forceinline__ int swzv(int v) { return v ^ ((v >> 4) & 7); }

// ---- fused setup + partial histogram --------------------------------------
// Blocks [0, NS): setup (weight cvt + b12 + prefused qk + x_src cvt).
// Blocks [NS, NS+NHIST): LDS-aggregated histogram, block hb WRITES its
// private partial to hp1[hb*nb1+i] / hp2[hb*nb2+i] (no zeroed globals).
__global__ __launch_bounds__(256) void setup_hist(
    const float* __restrict__ W1, const float* __restrict__ W2,
    const float* __restrict__ vw, const float* __restrict__ b1,
    const float* __restrict__ b2, const float* __restrict__ qw,
    const float* __restrict__ kw, const float* __restrict__ qb,
    const float* __restrict__ kb, const float* __restrict__ xsrc,
    f16* __restrict__ wh, float* __restrict__ b12,
    float* __restrict__ bqk, float* __restrict__ wqkb,
    float* __restrict__ cconst, f16* __restrict__ xs_h, int na4, int NS,
    const int* __restrict__ k1, int E1, int nb1, int* __restrict__ hp1,
    const int* __restrict__ k2, int E2, int nb2, int* __restrict__ hp2)
{
    __shared__ int h[512];
    int tid = threadIdx.x;
    if (blockIdx.x < NS) {
        int idx = blockIdx.x * 256 + tid;
        if (idx < 3 * 16384) {
            const float* src = (idx < 16384) ? W1 :
                               (idx < 2 * 16384) ? W2 : vw;
            wh[idx] = (f16)src[idx & 16383];
        } else if (idx < 3 * 16384 + 128) {
            int j = idx - 3 * 16384;
            b12[j] = b1[j] + b2[j];
        } else if (idx < 4 * 16384 + 128) {
            int e = idx - (3 * 16384 + 128);
            int col = e >> 7, i = e & 127;
            float s = 0.f;
            for (int j = 0; j < 128; ++j)
                s += qw[j * 128 + i] * kw[j * 128 + col];
            wh[3 * 16384 + col * 128 + i] = (f16)s;
        } else if (idx < 4 * 16384 + 256) {
            int t = idx - (4 * 16384 + 128);
            float s1 = 0.f, s2 = 0.f;
            for (int j = 0; j < 128; ++j) {
                s1 += qw[j * 128 + t] * kb[j];
                s2 += qb[j] * kw[j * 128 + t];
            }
            wqkb[t] = s1;
            bqk[t] = s2;
        } else if (idx == 4 * 16384 + 256) {
            float s3 = 0.f;
            for (int j = 0; j < 128; ++j) s3 += qb[j] * kb[j];
            cconst[0] = s3;
        } else {
            int j = idx - (4 * 16384 + 257);
            if (j < na4) {
                float4 v = ((const float4*)xsrc)[j];
                f16x4 o = {(f16)v.x, (f16)v.y, (f16)v.z, (f16)v.w};
                ((f16x4*)xs_h)[j] = o;
            }
        }
    } else {
        int hb = blockIdx.x - NS;
        for (int i = tid; i < nb1 + nb2; i += 256) h[i] = 0;
        __syncthreads();
        int stride = NHIST * 256;
        for (int e = hb * 256 + tid; e < E1; e += stride)
            atomicAdd(&h[k1[e] >> 8], 1);
        for (int e = hb * 256 + tid; e < E2; e += stride)
            atomicAdd(&h[nb1 + (k2[e] >> 8)], 1);
        __syncthreads();
        for (int i = tid; i < nb1; i += 256) hp1[hb * nb1 + i] = h[i];
        for (int i = tid; i < nb2; i += 256) hp2[hb * nb2 + i] = h[nb1 + i];
    }
}

// ---- scan: sum partials -> bases + cursors; zero S slots ------------------
__global__ __launch_bounds__(256) void coarse_scan(
    const int* __restrict__ hp1, int nb1, int E1, int* __restrict__ cb1, int* __restrict__ cur1p,
    const int* __restrict__ hp2, int nb2, int E2, int* __restrict__ cb2, int* __restrict__ cur2p,
    float* __restrict__ slots)
{
    __shared__ int sd[256];
    int tid = threadIdx.x;
    int v = 0;
    if (tid < nb1)
        for (int b = 0; b < NHIST; ++b) v += hp1[b * nb1 + tid];
    sd[tid] = v; __syncthreads();
    for (int d = 1; d < 256; d <<= 1) {
        int t = (tid >= d) ? sd[tid - d] : 0;
        __syncthreads(); sd[tid] += t; __syncthreads();
    }
    if (tid < nb1) { int ex = sd[tid] - v; cb1[tid] = ex; cur1p[tid * 16] = ex; }
    if (tid == 0) cb1[nb1] = E1;
    __syncthreads();
    int v2 = 0;
    if (tid < nb2)
        for (int b = 0; b < NHIST; ++b) v2 += hp2[b * nb2 + tid];
    sd[tid] = v2; __syncthreads();
    for (int d = 1; d < 256; d <<= 1) {
        int t = (tid >= d) ? sd[tid - d] : 0;
        __syncthreads(); sd[tid] += t; __syncthreads();
    }
    if (tid < nb2) { int ex = sd[tid] - v2; cb2[tid] = ex; cur2p[tid * 16] = ex; }
    if (tid == 0) cb2[nb2] = E2;
    for (int i = tid; i < 64 * 16; i += 256) slots[i] = 0.f;
}

// ---- CSR build: block-chunked pair scatter --------------------------------
__device__ __forceinline__ void scatter_chunk(
    const int* __restrict__ keys, const int* __restrict__ pay, int E,
    int* __restrict__ curp, int2* __restrict__ out,
    int* hist, int* base, int nbk, int chunk)
{
    int tid = threadIdx.x;
    int start = chunk * SP_CHUNK;
    if (start >= E) return;
    int end = start + SP_CHUNK; if (end > E) end = E;

    for (int i = tid; i < nbk; i += 256) hist[i] = 0;
    __syncthreads();
    for (int i = start + tid; i < end; i += 256)
        atomicAdd(&hist[keys[i] >> 8], 1);
    __syncthreads();
    for (int i = tid; i < nbk; i += 256) {
        int c = hist[i];
        base[i] = c ? atomicAdd(&curp[i * 16], c) : 0;
        hist[i] = 0;   // reuse as local cursor
    }
    __syncthreads();
    for (int i = start + tid; i < end; i += 256) {
        int key = keys[i];
        int b = key >> 8;
        int lp = atomicAdd(&hist[b], 1);
        out[base[b] + lp] = make_int2(key, pay[i]);
    }
}

__global__ __launch_bounds__(256) void scatter_pairs_blk(
    const int* __restrict__ ei1, int E1, int nb1, int* __restrict__ cur1p,
    int2* __restrict__ p1, int nch1,
    const int* __restrict__ ei2, int E2, int nb2, int* __restrict__ cur2p,
    int2* __restrict__ p2)
{
    __shared__ int hist[256];
    __shared__ int base[256];
    int b = blockIdx.x;
    if (b < nch1)
        scatter_chunk(ei1 + E1, ei1, E1, cur1p, p1, hist, base, nb1, b);
    else
        scatter_chunk(ei2 + E2, ei2, E2, cur2p, p2, hist, base, nb2, b - nch1);
}

// ---- CSR build: per-bucket counting sort -> off[] + payload[] -------------
__global__ __launch_bounds__(256) void bucket_sort(
    const int2* __restrict__ p1, const int* __restrict__ cb1, int nb1, int N1, int E1,
    int* __restrict__ off1, int* __restrict__ out1,
    const int2* __restrict__ p2, const int* __restrict__ cb2, int nb2, int N2, int E2,
    int* __restrict__ off2, int* __restrict__ out2)
{
    __shared__ int hist[256];
    __shared__ int scn[256];
    int kb = blockIdx.x;
    const int2* pairs; const int* cb; int N, E; int* offk; int* outp;
    if (kb < nb1) { pairs = p1; cb = cb1; N = N1; E = E1; offk = off1; outp = out1; }
    else { kb -= nb1; pairs = p2; cb = cb2; N = N2; E = E2; offk = off2; outp = out2; }
    int tid = threadIdx.x;
    int base = cb[kb], cnt = cb[kb + 1] - base;
    int key0 = kb << 8;
    int nk = N - key0; if (nk > 256) nk = 256;

    hist[tid] = 0;
    __syncthreads();
    for (int i = tid; i < cnt; i += 256)
        atomicAdd(&hist[pairs[base + i].x - key0], 1);
    __syncthreads();
    int v = hist[tid];
    scn[tid] = v; __syncthreads();
    for (int d = 1; d < 256; d <<= 1) {
        int t = (tid >= d) ? scn[tid - d] : 0;
        __syncthreads(); scn[tid] += t; __syncthreads();
    }
    int ex = scn[tid] - v;
    if (tid < nk) offk[key0 + tid] = base + ex;
    if (tid == 0 && key0 + nk == N) offk[N] = E;
    hist[tid] = ex;   // reuse as per-key cursor
    __syncthreads();
    for (int i = tid; i < cnt; i += 256) {
        int2 pr = pairs[base + i];
        int p = atomicAdd(&hist[pr.x - key0], 1);
        outp[base + p] = pr.y;
    }
}

// ---- fused pull1 + Q' GEMM ------------------------------------------------
// Blocks [0, gbp): pull1 (s[m] = sum x_src rows, deg[m]).
// Blocks [gbp, gbp+gbd): Qp = Xd@wqk'^T + bqk; qc = Xd.wqkb + cconst.
// qp depends only on setup outputs, so it runs here instead of after stage1.
__global__ __launch_bounds__(256) void pull_qp(
    const f16* __restrict__ xs, const int* __restrict__ off,
    const int* __restrict__ lst, f16* __restrict__ s,
    float* __restrict__ deg, int N, int gbp,
    const float* __restrict__ Xd, const f16* __restrict__ W,
    const float* __restrict__ bias, const float* __restrict__ wqkb,
    const float* __restrict__ cconst, f16* __restrict__ Qp,
    float* __restrict__ qc, int M)
{
    __shared__ f16 lw[16384];
    int tid = threadIdx.x;
    if (blockIdx.x < gbp) {
        // ---------------- pull1 ----------------
        int w = blockIdx.x * 4 + (tid >> 6);
        int l = tid & 63;
        if (w >= N) return;
        int b = off[w], e = off[w + 1];
        float ax = 0.f, ay = 0.f;
        for (int i = b; i < e; i += 16) {
            int idx[16];
            f16x2 a[16];
#pragma unroll
            for (int u = 0; u < 16; ++u) {
                int id = i + u;
                idx[u] = lst[(id < e) ? id : b];
            }
#pragma unroll
            for (int u = 0; u < 16; ++u)
                a[u] = *(const f16x2*)(xs + (size_t)idx[u] * 128 + l * 2);
#pragma unroll
            for (int u = 0; u < 16; ++u) {
                bool val = (i + u) < e;
                ax += val ? (float)a[u][0] : 0.f;
                ay += val ? (float)a[u][1] : 0.f;
            }
        }
        f16x2 o = {(f16)ax, (f16)ay};
        *(f16x2*)(s + (size_t)w * 128 + l * 2) = o;
        if (l == 0) deg[w] = (float)(e - b);
    } else {
        // ---------------- qp ----------------
        int lane = tid & 63;
        int r16 = lane & 15, quad = lane >> 4;
        int gw = ((blockIdx.x - gbp) * 256 + tid) >> 6;
        int mb = gw * 16;
        bool active = mb < M;
        int row = mb + r16; if (row >= M) row = M - 1;

        f32x4 alo[4], ahi[4];
        if (active) {
            const float* xp = Xd + (size_t)row * 128 + quad * 8;
#pragma unroll
            for (int kb = 0; kb < 4; ++kb) {
                alo[kb] = *(const f32x4*)(xp + kb * 32);
                ahi[kb] = *(const f32x4*)(xp + kb * 32 + 4);
            }
        }
        {
            const f16x8* gsrc = (const f16x8*)W;   // 2048 vectors
            f16x8* ldst = (f16x8*)lw;
#pragma unroll
            for (int u = 0; u < 8; ++u) {
                int i = u * 256 + tid;
                ldst[swzv(i)] = gsrc[i];
            }
        }
        __syncthreads();
        if (!active) return;

        f16x8 a[4];
        float pq = 0.f;
#pragma unroll
        for (int kb = 0; kb < 4; ++kb)
#pragma unroll
            for (int j = 0; j < 4; ++j) {
                a[kb][j] = (f16)alo[kb][j];
                a[kb][4 + j] = (f16)ahi[kb][j];
                pq += alo[kb][j] * wqkb[kb * 32 + quad * 8 + j];
                pq += ahi[kb][j] * wqkb[kb * 32 + quad * 8 + 4 + j];
            }

        f32x4 acc[8];
#pragma unroll
        for (int t = 0; t < 8; ++t) acc[t] = (f32x4){0.f, 0.f, 0.f, 0.f};
        const f16x8* lv = (const f16x8*)lw;
#pragma unroll
        for (int kb = 0; kb < 4; ++kb) {
#pragma unroll
            for (int t = 0; t < 8; ++t) {
                f16x8 b = lv[swzv((t * 16 + r16) * 16 + kb * 4 + quad)];
                acc[t] = __builtin_amdgcn_mfma_f32_16x16x32_f16(a[kb], b, acc[t], 0, 0, 0);
            }
        }
        pq += __shfl_xor(pq, 16);
        pq += __shfl_xor(pq, 32);
        if (quad == 0 && mb + r16 < M) qc[mb + r16] = pq + cconst[0];
#pragma unroll
        for (int t = 0; t < 8; ++t) {
            int col = t * 16 + r16;
            float bv = bias[col];
#pragma unroll
            for (int i = 0; i < 4; ++i) {
                int r = mb + quad * 4 + i;
                if (r < M) Qp[(size_t)r * 128 + col] = (f16)(acc[t][i] + bv);
            }
        }
    }
}

// ---- MFMA stage1: H = deg*(Xm@W1^T + b12) + S@W2^T ------------------------
__global__ __launch_bounds__(256) void gemm_stage1_mfma(
    const float* __restrict__ Xm, const f16* __restrict__ S,
    const f16* __restrict__ w12, const float* __restrict__ b12,
    const float* __restrict__ deg, f16* __restrict__ H, int M)
{
    __shared__ f16 lw[32768];   // w1 rows 0-127, w2 rows 128-255 (swizzled)
    int tid = threadIdx.x;
    int lane = tid & 63;
    int r16 = lane & 15, quad = lane >> 4;
    int gw = (blockIdx.x * 256 + tid) >> 6;
    int mb = gw * 16;
    bool active = mb < M;
    int row = mb + r16; if (row >= M) row = M - 1;

    f32x4 alo[4], ahi[4];
    f16x8 a2[4];
    if (active) {
        const float* xa = Xm + (size_t)row * 128 + quad * 8;
        const f16* xb = S + (size_t)row * 128 + quad * 8;
#pragma unroll
        for (int kb = 0; kb < 4; ++kb) {
            alo[kb] = *(const f32x4*)(xa + kb * 32);
            ahi[kb] = *(const f32x4*)(xa + kb * 32 + 4);
            a2[kb] = *(const f16x8*)(xb + kb * 32);
        }
    }
    {
        const f16x8* gsrc = (const f16x8*)w12;   // 4096 16B vectors
        f16x8* ldst = (f16x8*)lw;
#pragma unroll
        for (int u = 0; u < 16; ++u) {
            int i = u * 256 + tid;
            ldst[swzv(i)] = gsrc[i];
        }
    }
    __syncthreads();
    if (!active) return;

    f16x8 a1[4];
#pragma unroll
    for (int kb = 0; kb < 4; ++kb)
#pragma unroll
        for (int j = 0; j < 4; ++j) {
            a1[kb][j] = (f16)alo[kb][j];
            a1[kb][4 + j] = (f16)ahi[kb][j];
        }

    f32x4 accA[8], accB[8];
#pragma unroll
    for (int t = 0; t < 8; ++t) {
        accA[t] = (f32x4){0.f, 0.f, 0.f, 0.f};
        accB[t] = (f32x4){0.f, 0.f, 0.f, 0.f};
    }
    const f16x8* lv = (const f16x8*)lw;
#pragma unroll
    for (int kb = 0; kb < 4; ++kb) {
#pragma unroll
        for (int t = 0; t < 8; ++t) {
            int r = t * 16 + r16;
            f16x8 bw1 = lv[swzv(r * 16 + kb * 4 + quad)];
            f16x8 bw2 = lv[swzv((r + 128) * 16 + kb * 4 + quad)];
            accA[t] = __builtin_amdgcn_mfma_f32_16x16x32_f16(a1[kb], bw1, accA[t], 0, 0, 0);
            accB[t] = __builtin_amdgcn_mfma_f32_16x16x32_f16(a2[kb], bw2, accB[t], 0, 0, 0);
        }
    }
    float dv[4];
#pragma unroll
    for (int i = 0; i < 4; ++i) {
        int r = mb + quad * 4 + i;
        dv[i] = (r < M) ? deg[r] : 0.f;
    }
#pragma unroll
    for (int t = 0; t < 8; ++t) {
        int col = t * 16 + r16;
        float bb = b12[col];
#pragma unroll
        for (int i = 0; i < 4; ++i) {
            int r = mb + quad * 4 + i;
            if (r < M)
                H[(size_t)r * 128 + col] = (f16)(dv[i] * (accA[t][i] + bb) + accB[t][i]);
        }
    }
}

// ---- MFMA V: out = (U^@wv^T + vb) * sexp/S; S = sum of 64 slots -----------
__global__ __launch_bounds__(256) void gemm_v_mfma(
    const f16* U, const f16* __restrict__ W,
    const float* __restrict__ vb, const float* __restrict__ sexp,
    const float* __restrict__ slots, float* __restrict__ out, int M)
{
    __shared__ f16 lw[16384];
    int tid = threadIdx.x;
    int lane = tid & 63;
    int r16 = lane & 15, quad = lane >> 4;
    int gw = (blockIdx.x * 256 + tid) >> 6;
    int mb = gw * 16;
    bool active = mb < M;
    int row = mb + r16; if (row >= M) row = M - 1;

    f16x8 a[4];
    if (active) {
        const f16* xp = U + (size_t)row * 128 + quad * 8;
#pragma unroll
        for (int kb = 0; kb < 4; ++kb)
            a[kb] = *(const f16x8*)(xp + kb * 32);
    }
    {
        const f16x8* gsrc = (const f16x8*)W;
        f16x8* ldst = (f16x8*)lw;
#pragma unroll
        for (int u = 0; u < 8; ++u) {
            int i = u * 256 + tid;
            ldst[swzv(i)] = gsrc[i];
        }
    }
    // S = sum of the 64 padded slots (one per lane, 64-lane shuffle reduce)
    float sv_ = slots[lane * 16];
#pragma unroll
    for (int o = 1; o < 64; o <<= 1) sv_ += __shfl_xor(sv_, o);
    float invS = 1.0f / sv_;

    __syncthreads();
    if (!active) return;

    f32x4 acc[8];
#pragma unroll
    for (int t = 0; t < 8; ++t) acc[t] = (f32x4){0.f, 0.f, 0.f, 0.f};

    const f16x8* lv = (const f16x8*)lw;
#pragma unroll
    for (int kb = 0; kb < 4; ++kb) {
#pragma unroll
        for (int t = 0; t < 8; ++t) {
            f16x8 b = lv[swzv((t * 16 + r16) * 16 + kb * 4 + quad)];
            acc[t] = __builtin_amdgcn_mfma_f32_16x16x32_f16(a[kb], b, acc[t], 0, 0, 0);
        }
    }
    float sv[4];
#pragma unroll
    for (int i = 0; i < 4; ++i) {
        int r = mb + quad * 4 + i;
        sv[i] = (r < M) ? sexp[r] * invS : 0.f;
    }
#pragma unroll
    for (int t = 0; t < 8; ++t) {
        int col = t * 16 + r16;
        float bv = vb[col];
#pragma unroll
        for (int i = 0; i < 4; ++i) {
            int r = mb + quad * 4 + i;
            if (r < M)
                out[(size_t)r * 128 + col] = (acc[t][i] + bv) * sv[i];
        }
    }
}

// ---- fused attention: one wave per dst, h-only gather; 64-slot S ----------
__global__ __launch_bounds__(256) void attn_fused_h(
    const f16* __restrict__ Qp, const f16* __restrict__ H,
    const float* __restrict__ qc, const int* __restrict__ off,
    const int* __restrict__ lstm, f16* __restrict__ U,
    float* __restrict__ sexp, float* __restrict__ slots, int N)
{
    const int tid  = threadIdx.x;
    const int w    = blockIdx.x * 4 + (tid >> 6);
    const int lane = tid & 63;
    const int sub  = lane >> 4;
    const int c    = lane & 15;
    const float scale = 0.08838834764831845f;  // 1/sqrt(128)

    float acc[8];
#pragma unroll
    for (int j = 0; j < 8; ++j) acc[j] = 0.f;
    float ssum = 0.f;
    float factor = 0.f;

    if (w < N) {
        factor = __expf(qc[w] * scale);
        int b = off[w], e = off[w + 1];
        if (b < e) {
            f16x8 qh = *(const f16x8*)(Qp + (size_t)w * 128 + c * 8);
            f16x2 q2[4];
#pragma unroll
            for (int j = 0; j < 4; ++j) q2[j] = ((const f16x2*)&qh)[j];
            for (int i = b; i < e; i += 16) {
                int m[4]; bool val[4];
#pragma unroll
                for (int u = 0; u < 4; ++u) {
                    int id = i + sub * 4 + u;
                    val[u] = id < e;
                    m[u] = lstm[val[u] ? id : b];
                }
                f16x8 hh[4];
#pragma unroll
                for (int u = 0; u < 4; ++u)
                    hh[u] = *(const f16x8*)(H + (size_t)m[u] * 128 + c * 8);
                float p[4];
#pragma unroll
                for (int u = 0; u < 4; ++u) {
                    float s = 0.f;
                    const f16x2* h2 = (const f16x2*)&hh[u];
#pragma unroll
                    for (int j = 0; j < 4; ++j)
#if __has_builtin(__builtin_amdgcn_fdot2)
                        s = __builtin_amdgcn_fdot2(q2[j], h2[j], s, false);
#else
                        s += (float)q2[j][0] * (float)h2[j][0]
                           + (float)q2[j][1] * (float)h2[j][1];
#endif
                    p[u] = s;
                }
#pragma unroll
                for (int o = 1; o < 16; o <<= 1) {
#pragma unroll
                    for (int u = 0; u < 4; ++u)
                        p[u] += __shfl_xor(p[u], o);
                }
                float a[4];
#pragma unroll
                for (int u = 0; u < 4; ++u)
                    a[u] = val[u] ? __expf(p[u] * scale) : 0.f;
                ssum += (a[0] + a[1]) + (a[2] + a[3]);
#pragma unroll
                for (int u = 0; u < 4; ++u)
#pragma unroll
                    for (int j = 0; j < 8; ++j)
                        acc[j] += a[u] * (float)hh[u][j];
            }
        }
    }
    float stot = ssum;
    stot += __shfl_xor(stot, 16);
    stot += __shfl_xor(stot, 32);

    if (w < N) {
#pragma unroll
        for (int j = 0; j < 8; ++j) {
            acc[j] += __shfl_xor(acc[j], 16);
            acc[j] += __shfl_xor(acc[j], 32);
        }
        if (sub == 0) {
            float inv = (stot > 0.f) ? 1.0f / stot : 0.f;
            f16x8 o;
#pragma unroll
            for (int j = 0; j < 8; ++j) o[j] = (f16)(acc[j] * inv);
            *(f16x8*)(U + (size_t)w * 128 + c * 8) = o;
        }
    }
    float sg = stot * factor;   // 0 for w>=N
    if (lane == 0 && w < N) sexp[w] = sg;
    __shared__ float bs[4];
    if (lane == 0) bs[tid >> 6] = sg;
    __syncthreads();
    if (tid == 0) {
        float t = bs[0] + bs[1] + bs[2] + bs[3];
        if (t != 0.f) atomicAdd(&slots[(blockIdx.x & 63) * 16], t);
    }
}

// ---------------------------------------------------------------------------
extern "C" void kernel_launch(void* const* d_in, const int* in_sizes, int n_in,
                              void* d_out, int out_size, void* d_ws, size_t ws_size,
                              hipStream_t stream)
{
    const float* x_src = (const float*)d_in[0];
    const float* x_mid = (const float*)d_in[1];
    const float* x_dst = (const float*)d_in[2];
    const int*   ei1   = (const int*)d_in[3];
    const int*   ei2   = (const int*)d_in[4];
    const float* W1_w  = (const float*)d_in[5];
    const float* W1_b  = (const float*)d_in[6];
    const float* W2_w  = (const float*)d_in[7];
    const float* W2_b  = (const float*)d_in[8];
    const float* q_w   = (const float*)d_in[9];
    const float* q_b   = (const float*)d_in[10];
    const float* k_w   = (const float*)d_in[11];
    const float* k_b   = (const float*)d_in[12];
    const float* v_w   = (const float*)d_in[13];
    const float* v_b   = (const float*)d_in[14];

    const int NSRC = in_sizes[0] / 128;
    const int NMID = in_sizes[1] / 128;
    const int NDST = in_sizes[2] / 128;
    const int E1   = in_sizes[3] / 2;
    const int E2   = in_sizes[4] / 2;
    const int nb2g = (NDST + 3) / 4;               // attn grid
    const int nb1  = (NMID + 255) >> 8;            // coarse buckets
    const int nb2  = (NDST + 255) >> 8;

    auto al4 = [](size_t n) { return (n + 3) & ~(size_t)3; };

    // ---- workspace layout ----
    f16* xs_h = (f16*)d_ws;                        // NSRC*128
    f16* h_h  = xs_h + (size_t)NSRC * 128;         // NMID*128 (H)
    f16* s_h  = h_h + (size_t)NMID * 128;          // NMID*128
    f16* qp_h = s_h + (size_t)NMID * 128;          // NDST*128 (Q')
    f16* u_h  = qp_h + (size_t)NDST * 128;         // NDST*128 (U^)
    f16* w_h  = u_h + (size_t)NDST * 128;          // 4*16384
    f16* wvh = w_h + 2 * 16384;
    f16* wqk = w_h + 3 * 16384;

    float* b12 = (float*)(w_h + 4 * 16384);        // 128
    float* bqk = b12 + 128;                        // 128
    float* wqkb = bqk + 128;                       // 128
    float* cconst = wqkb + 128;                    // 4
    float* deg = cconst + 4;                       // NMID
    float* qcv = deg + al4(NMID);                  // NDST
    float* sexp = qcv + al4(NDST);                 // NDST
    float* slots = sexp + al4(NDST);               // 64*16 (padded S slots)

    int2* pairs1 = (int2*)(slots + 64 * 16);       // E1  (8B-aligned by layout)
    int2* pairs2 = pairs1 + E1;                    // E2
    int*  cb1   = (int*)(pairs2 + E2);             // nb1+1
    int*  cb2   = cb1 + al4(nb1 + 1);              // nb2+1
    int*  hp1   = cb2 + al4(nb2 + 1);              // NHIST*nb1 (partial hists)
    int*  hp2   = hp1 + NHIST * nb1;               // NHIST*nb2
    int*  cur1p = hp2 + NHIST * nb2;               // nb1*16
    int*  cur2p = cur1p + nb1 * 16;                // nb2*16
    int*  off1  = cur2p + nb2 * 16;                // NMID+1
    int*  off2  = off1 + al4(NMID + 1);            // NDST+1
    int*  lst1  = off2 + al4(NDST + 1);            // E1 (src, grouped by mid)
    int*  lstm2 = lst1 + al4(E1);                  // E2 (mid, grouped by dst)

    // ---- fused setup + partial histogram ----
    {
        int na4 = NSRC * 32;
        int totalA = 4 * 16384 + 257 + na4;
        int NS = (totalA + 255) / 256;
        setup_hist<<<NS + NHIST, 256, 0, stream>>>(
            W1_w, W2_w, v_w, W1_b, W2_b, q_w, k_w, q_b, k_b, x_src,
            w_h, b12, bqk, wqkb, cconst, xs_h, na4, NS,
            ei1 + E1, E1, nb1, hp1,
            ei2 + E2, E2, nb2, hp2);
    }
    coarse_scan<<<1, 256, 0, stream>>>(hp1, nb1, E1, cb1, cur1p,
                                       hp2, nb2, E2, cb2, cur2p, slots);
    {
        int nch1 = (E1 + SP_CHUNK - 1) / SP_CHUNK;
        int nch2 = (E2 + SP_CHUNK - 1) / SP_CHUNK;
        scatter_pairs_blk<<<nch1 + nch2, 256, 0, stream>>>(
            ei1, E1, nb1, cur1p, pairs1, nch1,
            ei2, E2, nb2, cur2p, pairs2);
    }
    bucket_sort<<<nb1 + nb2, 256, 0, stream>>>(
        pairs1, cb1, nb1, NMID, E1, off1, lst1,
        pairs2, cb2, nb2, NDST, E2, off2, lstm2);

    // ---- pull1 + Q' (fused, independent halves) ----
    int gbp = (NMID + 3) / 4;
    int gbd = ((NDST + 15) / 16 + 3) / 4;
    pull_qp<<<gbp + gbd, 256, 0, stream>>>(
        xs_h, off1, lst1, s_h, deg, NMID, gbp,
        x_dst, wqk, bqk, wqkb, cconst, qp_h, qcv, NDST);

    int gbm = ((NMID + 15) / 16 + 3) / 4;
    gemm_stage1_mfma<<<gbm, 256, 0, stream>>>(x_mid, s_h, w_h /*w1|w2*/, b12,
                                              deg, h_h, NMID);

    // ---- fused attention (h-gather) + projection/normalize ----
    attn_fused_h<<<nb2g, 256, 0, stream>>>(qp_h, h_h, qcv, off2, lstm2,
                                           u_h, sexp, slots, NDST);
    gemm_v_mfma<<<gbd, 256, 0, stream>>>(u_h, wvh, v_b, sexp, slots,
                                         (float*)d_out, NDST);
}

// Round 12
// 325.128 us; speedup vs baseline: 1.7696x; 1.0403x over previous
//
#include <hip/hip_runtime.h>
#include <cstdint>
#include <cstddef>

// ---------------------------------------------------------------------------
// AtomicRouteConv, sort-based CSR + fp16 MFMA pipeline.
//   R1: scatter occupancy fix (SP_CHUNK 2048, one chunk/list per block).
//   R2: MFMA QK^T in attn -> REGRESSED (latency-bound). Reverted.
//   R3: 16-edge tiles + fdot2 in attn; pull1 16-wide.
//   R4/R5: algebraic K/V elimination; U stored locally-normalized (f16-safe).
//   R6: GEMM weight LDS staging (XOR-swizzled). 344us.
//   R7: CRASHED (fused dual-MFMA s1qp kernel; dropped).
//   R8: single-float atomic-S REGRESSED (one-cache-line serialization).
//   R9: contention-free partial[]+reduce; setup fusion; f32 A-reads. 325.8us.
//   R10: cooperative grid.sync CSR REGRESSED HARD (grid.sync ~70us each).
//   R11: setup+hist fused, no-memset partial hists, 64-slot S all GOOD, but
//   pull1+qp fusion REGRESSED (63.9us, occ 23%): qp's static 32KB LDS is
//   charged to ALL blocks -> latency-bound pull1 capped at 20 waves/CU.
//   Also: R9->R11 launch-count math shows gaps are ~1-3us, not 12 -> residual
//   time is IN-KERNEL; only LDS-free fusions are worthwhile.
//   R12: un-fuse pull1/qp (R9-proven separate kernels); keep R11 (a),(b),(d).
//   9 launches.
//   CSR1 (by mid): s[m] = sum x_src rows (f16 gather, f32 acc), deg[m]
//   h = deg*(x_mid@W1^T + b12) + s@W2^T      (MFMA; x_mid read f32)
//   Q' = x_dst@(q_w^T k_w)+q_b k_w (prefused); qc = x_dst.wqkb + qb.kb
//   CSR2 (by dst), one wave per dst: U^ = sum(a*h)/sum(a), sexp = f*sum(a)
//   out = sexp/S * (U^@v_w^T + v_b);  S = 64 padded atomic slots.
// NOTE: bucket = key>>8 requires N <= 65536 (here N=50000).
// ---------------------------------------------------------------------------

using f16   = _Float16;
using f16x2 = __attribute__((ext_vector_type(2))) _Float16;
using f16x4 = __attribute__((ext_vector_type(4))) _Float16;
using f16x8 = __attribute__((ext_vector_type(8))) _Float16;
using f32x4 = __attribute__((ext_vector_type(4))) float;

#define SP_CHUNK 2048
#define NHIST 64

// LDS swizzle on 16B-vector index: XOR row&7 (row = vec>>4) into bits [0:2].
// B-fragment read (r16 strided 256B) 16-way -> 2-way bank conflict (free).
__device__ __forceinline__ int swzv(int v) { return v ^ ((v >> 4) & 7); }

// ---- fused setup + partial histogram --------------------------------------
// Blocks [0, NS): setup (weight cvt + b12 + prefused qk + x_src cvt).
// Blocks [NS, NS+NHIST): LDS-aggregated histogram, block hb WRITES its
// private partial to hp1[hb*nb1+i] / hp2[hb*nb2+i] (no zeroed globals).
__global__ __launch_bounds__(256) void setup_hist(
    const float* __restrict__ W1, const float* __restrict__ W2,
    const float* __restrict__ vw, const float* __restrict__ b1,
    const float* __restrict__ b2, const float* __restrict__ qw,
    const float* __restrict__ kw, const float* __restrict__ qb,
    const float* __restrict__ kb, const float* __restrict__ xsrc,
    f16* __restrict__ wh, float* __restrict__ b12,
    float* __restrict__ bqk, float* __restrict__ wqkb,
    float* __restrict__ cconst, f16* __restrict__ xs_h, int na4, int NS,
    const int* __restrict__ k1, int E1, int nb1, int* __restrict__ hp1,
    const int* __restrict__ k2, int E2, int nb2, int* __restrict__ hp2)
{
    __shared__ int h[512];
    int tid = threadIdx.x;
    if (blockIdx.x < NS) {
        int idx = blockIdx.x * 256 + tid;
        if (idx < 3 * 16384) {
            const float* src = (idx < 16384) ? W1 :
                               (idx < 2 * 16384) ? W2 : vw;
            wh[idx] = (f16)src[idx & 16383];
        } else if (idx < 3 * 16384 + 128) {
            int j = idx - 3 * 16384;
            b12[j] = b1[j] + b2[j];
        } else if (idx < 4 * 16384 + 128) {
            int e = idx - (3 * 16384 + 128);
            int col = e >> 7, i = e & 127;
            float s = 0.f;
            for (int j = 0; j < 128; ++j)
                s += qw[j * 128 + i] * kw[j * 128 + col];
            wh[3 * 16384 + col * 128 + i] = (f16)s;
        } else if (idx < 4 * 16384 + 256) {
            int t = idx - (4 * 16384 + 128);
            float s1 = 0.f, s2 = 0.f;
            for (int j = 0; j < 128; ++j) {
                s1 += qw[j * 128 + t] * kb[j];
                s2 += qb[j] * kw[j * 128 + t];
            }
            wqkb[t] = s1;
            bqk[t] = s2;
        } else if (idx == 4 * 16384 + 256) {
            float s3 = 0.f;
            for (int j = 0; j < 128; ++j) s3 += qb[j] * kb[j];
            cconst[0] = s3;
        } else {
            int j = idx - (4 * 16384 + 257);
            if (j < na4) {
                float4 v = ((const float4*)xsrc)[j];
                f16x4 o = {(f16)v.x, (f16)v.y, (f16)v.z, (f16)v.w};
                ((f16x4*)xs_h)[j] = o;
            }
        }
    } else {
        int hb = blockIdx.x - NS;
        for (int i = tid; i < nb1 + nb2; i += 256) h[i] = 0;
        __syncthreads();
        int stride = NHIST * 256;
        for (int e = hb * 256 + tid; e < E1; e += stride)
            atomicAdd(&h[k1[e] >> 8], 1);
        for (int e = hb * 256 + tid; e < E2; e += stride)
            atomicAdd(&h[nb1 + (k2[e] >> 8)], 1);
        __syncthreads();
        for (int i = tid; i < nb1; i += 256) hp1[hb * nb1 + i] = h[i];
        for (int i = tid; i < nb2; i += 256) hp2[hb * nb2 + i] = h[nb1 + i];
    }
}

// ---- scan: sum partials -> bases + cursors; zero S slots ------------------
__global__ __launch_bounds__(256) void coarse_scan(
    const int* __restrict__ hp1, int nb1, int E1, int* __restrict__ cb1, int* __restrict__ cur1p,
    const int* __restrict__ hp2, int nb2, int E2, int* __restrict__ cb2, int* __restrict__ cur2p,
    float* __restrict__ slots)
{
    __shared__ int sd[256];
    int tid = threadIdx.x;
    int v = 0;
    if (tid < nb1)
        for (int b = 0; b < NHIST; ++b) v += hp1[b * nb1 + tid];
    sd[tid] = v; __syncthreads();
    for (int d = 1; d < 256; d <<= 1) {
        int t = (tid >= d) ? sd[tid - d] : 0;
        __syncthreads(); sd[tid] += t; __syncthreads();
    }
    if (tid < nb1) { int ex = sd[tid] - v; cb1[tid] = ex; cur1p[tid * 16] = ex; }
    if (tid == 0) cb1[nb1] = E1;
    __syncthreads();
    int v2 = 0;
    if (tid < nb2)
        for (int b = 0; b < NHIST; ++b) v2 += hp2[b * nb2 + tid];
    sd[tid] = v2; __syncthreads();
    for (int d = 1; d < 256; d <<= 1) {
        int t = (tid >= d) ? sd[tid - d] : 0;
        __syncthreads(); sd[tid] += t; __syncthreads();
    }
    if (tid < nb2) { int ex = sd[tid] - v2; cb2[tid] = ex; cur2p[tid * 16] = ex; }
    if (tid == 0) cb2[nb2] = E2;
    for (int i = tid; i < 64 * 16; i += 256) slots[i] = 0.f;
}

// ---- CSR build: block-chunked pair scatter --------------------------------
__device__ __forceinline__ void scatter_chunk(
    const int* __restrict__ keys, const int* __restrict__ pay, int E,
    int* __restrict__ curp, int2* __restrict__ out,
    int* hist, int* base, int nbk, int chunk)
{
    int tid = threadIdx.x;
    int start = chunk * SP_CHUNK;
    if (start >= E) return;
    int end = start + SP_CHUNK; if (end > E) end = E;

    for (int i = tid; i < nbk; i += 256) hist[i] = 0;
    __syncthreads();
    for (int i = start + tid; i < end; i += 256)
        atomicAdd(&hist[keys[i] >> 8], 1);
    __syncthreads();
    for (int i = tid; i < nbk; i += 256) {
        int c = hist[i];
        base[i] = c ? atomicAdd(&curp[i * 16], c) : 0;
        hist[i] = 0;   // reuse as local cursor
    }
    __syncthreads();
    for (int i = start + tid; i < end; i += 256) {
        int key = keys[i];
        int b = key >> 8;
        int lp = atomicAdd(&hist[b], 1);
        out[base[b] + lp] = make_int2(key, pay[i]);
    }
}

__global__ __launch_bounds__(256) void scatter_pairs_blk(
    const int* __restrict__ ei1, int E1, int nb1, int* __restrict__ cur1p,
    int2* __restrict__ p1, int nch1,
    const int* __restrict__ ei2, int E2, int nb2, int* __restrict__ cur2p,
    int2* __restrict__ p2)
{
    __shared__ int hist[256];
    __shared__ int base[256];
    int b = blockIdx.x;
    if (b < nch1)
        scatter_chunk(ei1 + E1, ei1, E1, cur1p, p1, hist, base, nb1, b);
    else
        scatter_chunk(ei2 + E2, ei2, E2, cur2p, p2, hist, base, nb2, b - nch1);
}

// ---- CSR build: per-bucket counting sort -> off[] + payload[] -------------
__global__ __launch_bounds__(256) void bucket_sort(
    const int2* __restrict__ p1, const int* __restrict__ cb1, int nb1, int N1, int E1,
    int* __restrict__ off1, int* __restrict__ out1,
    const int2* __restrict__ p2, const int* __restrict__ cb2, int nb2, int N2, int E2,
    int* __restrict__ off2, int* __restrict__ out2)
{
    __shared__ int hist[256];
    __shared__ int scn[256];
    int kb = blockIdx.x;
    const int2* pairs; const int* cb; int N, E; int* offk; int* outp;
    if (kb < nb1) { pairs = p1; cb = cb1; N = N1; E = E1; offk = off1; outp = out1; }
    else { kb -= nb1; pairs = p2; cb = cb2; N = N2; E = E2; offk = off2; outp = out2; }
    int tid = threadIdx.x;
    int base = cb[kb], cnt = cb[kb + 1] - base;
    int key0 = kb << 8;
    int nk = N - key0; if (nk > 256) nk = 256;

    hist[tid] = 0;
    __syncthreads();
    for (int i = tid; i < cnt; i += 256)
        atomicAdd(&hist[pairs[base + i].x - key0], 1);
    __syncthreads();
    int v = hist[tid];
    scn[tid] = v; __syncthreads();
    for (int d = 1; d < 256; d <<= 1) {
        int t = (tid >= d) ? scn[tid - d] : 0;
        __syncthreads(); scn[tid] += t; __syncthreads();
    }
    int ex = scn[tid] - v;
    if (tid < nk) offk[key0 + tid] = base + ex;
    if (tid == 0 && key0 + nk == N) offk[N] = E;
    hist[tid] = ex;   // reuse as per-key cursor
    __syncthreads();
    for (int i = tid; i < cnt; i += 256) {
        int2 pr = pairs[base + i];
        int p = atomicAdd(&hist[pr.x - key0], 1);
        outp[base + p] = pr.y;
    }
}

// ---- pull1: s[m] = sum of fp16 x_src rows; deg[m] (no LDS, max occ) -------
__global__ __launch_bounds__(256) void pull1_h(
    const f16* __restrict__ xs, const int* __restrict__ off,
    const int* __restrict__ lst, f16* __restrict__ s,
    float* __restrict__ deg, int N)
{
    int w = blockIdx.x * 4 + (threadIdx.x >> 6);
    int l = threadIdx.x & 63;
    if (w >= N) return;
    int b = off[w], e = off[w + 1];
    float ax = 0.f, ay = 0.f;
    for (int i = b; i < e; i += 16) {
        int idx[16];
        f16x2 a[16];
#pragma unroll
        for (int u = 0; u < 16; ++u) {
            int id = i + u;
            idx[u] = lst[(id < e) ? id : b];
        }
#pragma unroll
        for (int u = 0; u < 16; ++u)
            a[u] = *(const f16x2*)(xs + (size_t)idx[u] * 128 + l * 2);
#pragma unroll
        for (int u = 0; u < 16; ++u) {
            bool val = (i + u) < e;
            ax += val ? (float)a[u][0] : 0.f;
            ay += val ? (float)a[u][1] : 0.f;
        }
    }
    f16x2 o = {(f16)ax, (f16)ay};
    *(f16x2*)(s + (size_t)w * 128 + l * 2) = o;
    if (l == 0) deg[w] = (float)(e - b);
}

// ---- MFMA Q': Qp = Xd@wqk'^T + bqk; qc = Xd.wqkb + cconst (Xd f32) --------
__global__ __launch_bounds__(256) void gemm_qp_mfma(
    const float* __restrict__ Xd, const f16* __restrict__ W,
    const float* __restrict__ bias, const float* __restrict__ wqkb,
    const float* __restrict__ cconst, f16* __restrict__ Qp,
    float* __restrict__ qc, int M)
{
    __shared__ f16 lw[16384];
    int tid = threadIdx.x;
    int lane = tid & 63;
    int r16 = lane & 15, quad = lane >> 4;
    int gw = (blockIdx.x * 256 + tid) >> 6;
    int mb = gw * 16;
    bool active = mb < M;
    int row = mb + r16; if (row >= M) row = M - 1;

    f32x4 alo[4], ahi[4];
    if (active) {
        const float* xp = Xd + (size_t)row * 128 + quad * 8;
#pragma unroll
        for (int kb = 0; kb < 4; ++kb) {
            alo[kb] = *(const f32x4*)(xp + kb * 32);
            ahi[kb] = *(const f32x4*)(xp + kb * 32 + 4);
        }
    }
    {
        const f16x8* gsrc = (const f16x8*)W;   // 2048 vectors
        f16x8* ldst = (f16x8*)lw;
#pragma unroll
        for (int u = 0; u < 8; ++u) {
            int i = u * 256 + tid;
            ldst[swzv(i)] = gsrc[i];
        }
    }
    __syncthreads();
    if (!active) return;

    f16x8 a[4];
    float pq = 0.f;
#pragma unroll
    for (int kb = 0; kb < 4; ++kb)
#pragma unroll
        for (int j = 0; j < 4; ++j) {
            a[kb][j] = (f16)alo[kb][j];
            a[kb][4 + j] = (f16)ahi[kb][j];
            pq += alo[kb][j] * wqkb[kb * 32 + quad * 8 + j];
            pq += ahi[kb][j] * wqkb[kb * 32 + quad * 8 + 4 + j];
        }

    f32x4 acc[8];
#pragma unroll
    for (int t = 0; t < 8; ++t) acc[t] = (f32x4){0.f, 0.f, 0.f, 0.f};
    const f16x8* lv = (const f16x8*)lw;
#pragma unroll
    for (int kb = 0; kb < 4; ++kb) {
#pragma unroll
        for (int t = 0; t < 8; ++t) {
            f16x8 b = lv[swzv((t * 16 + r16) * 16 + kb * 4 + quad)];
            acc[t] = __builtin_amdgcn_mfma_f32_16x16x32_f16(a[kb], b, acc[t], 0, 0, 0);
        }
    }
    pq += __shfl_xor(pq, 16);
    pq += __shfl_xor(pq, 32);
    if (quad == 0 && mb + r16 < M) qc[mb + r16] = pq + cconst[0];
#pragma unroll
    for (int t = 0; t < 8; ++t) {
        int col = t * 16 + r16;
        float bv = bias[col];
#pragma unroll
        for (int i = 0; i < 4; ++i) {
            int r = mb + quad * 4 + i;
            if (r < M) Qp[(size_t)r * 128 + col] = (f16)(acc[t][i] + bv);
        }
    }
}

// ---- MFMA stage1: H = deg*(Xm@W1^T + b12) + S@W2^T ------------------------
__global__ __launch_bounds__(256) void gemm_stage1_mfma(
    const float* __restrict__ Xm, const f16* __restrict__ S,
    const f16* __restrict__ w12, const float* __restrict__ b12,
    const float* __restrict__ deg, f16* __restrict__ H, int M)
{
    __shared__ f16 lw[32768];   // w1 rows 0-127, w2 rows 128-255 (swizzled)
    int tid = threadIdx.x;
    int lane = tid & 63;
    int r16 = lane & 15, quad = lane >> 4;
    int gw = (blockIdx.x * 256 + tid) >> 6;
    int mb = gw * 16;
    bool active = mb < M;
    int row = mb + r16; if (row >= M) row = M - 1;

    f32x4 alo[4], ahi[4];
    f16x8 a2[4];
    if (active) {
        const float* xa = Xm + (size_t)row * 128 + quad * 8;
        const f16* xb = S + (size_t)row * 128 + quad * 8;
#pragma unroll
        for (int kb = 0; kb < 4; ++kb) {
            alo[kb] = *(const f32x4*)(xa + kb * 32);
            ahi[kb] = *(const f32x4*)(xa + kb * 32 + 4);
            a2[kb] = *(const f16x8*)(xb + kb * 32);
        }
    }
    {
        const f16x8* gsrc = (const f16x8*)w12;   // 4096 16B vectors
        f16x8* ldst = (f16x8*)lw;
#pragma unroll
        for (int u = 0; u < 16; ++u) {
            int i = u * 256 + tid;
            ldst[swzv(i)] = gsrc[i];
        }
    }
    __syncthreads();
    if (!active) return;

    f16x8 a1[4];
#pragma unroll
    for (int kb = 0; kb < 4; ++kb)
#pragma unroll
        for (int j = 0; j < 4; ++j) {
            a1[kb][j] = (f16)alo[kb][j];
            a1[kb][4 + j] = (f16)ahi[kb][j];
        }

    f32x4 accA[8], accB[8];
#pragma unroll
    for (int t = 0; t < 8; ++t) {
        accA[t] = (f32x4){0.f, 0.f, 0.f, 0.f};
        accB[t] = (f32x4){0.f, 0.f, 0.f, 0.f};
    }
    const f16x8* lv = (const f16x8*)lw;
#pragma unroll
    for (int kb = 0; kb < 4; ++kb) {
#pragma unroll
        for (int t = 0; t < 8; ++t) {
            int r = t * 16 + r16;
            f16x8 bw1 = lv[swzv(r * 16 + kb * 4 + quad)];
            f16x8 bw2 = lv[swzv((r + 128) * 16 + kb * 4 + quad)];
            accA[t] = __builtin_amdgcn_mfma_f32_16x16x32_f16(a1[kb], bw1, accA[t], 0, 0, 0);
            accB[t] = __builtin_amdgcn_mfma_f32_16x16x32_f16(a2[kb], bw2, accB[t], 0, 0, 0);
        }
    }
    float dv[4];
#pragma unroll
    for (int i = 0; i < 4; ++i) {
        int r = mb + quad * 4 + i;
        dv[i] = (r < M) ? deg[r] : 0.f;
    }
#pragma unroll
    for (int t = 0; t < 8; ++t) {
        int col = t * 16 + r16;
        float bb = b12[col];
#pragma unroll
        for (int i = 0; i < 4; ++i) {
            int r = mb + quad * 4 + i;
            if (r < M)
                H[(size_t)r * 128 + col] = (f16)(dv[i] * (accA[t][i] + bb) + accB[t][i]);
        }
    }
}

// ---- MFMA V: out = (U^@wv^T + vb) * sexp/S; S = sum of 64 slots -----------
__global__ __launch_bounds__(256) void gemm_v_mfma(
    const f16* U, const f16* __restrict__ W,
    const float* __restrict__ vb, const float* __restrict__ sexp,
    const float* __restrict__ slots, float* __restrict__ out, int M)
{
    __shared__ f16 lw[16384];
    int tid = threadIdx.x;
    int lane = tid & 63;
    int r16 = lane & 15, quad = lane >> 4;
    int gw = (blockIdx.x * 256 + tid) >> 6;
    int mb = gw * 16;
    bool active = mb < M;
    int row = mb + r16; if (row >= M) row = M - 1;

    f16x8 a[4];
    if (active) {
        const f16* xp = U + (size_t)row * 128 + quad * 8;
#pragma unroll
        for (int kb = 0; kb < 4; ++kb)
            a[kb] = *(const f16x8*)(xp + kb * 32);
    }
    {
        const f16x8* gsrc = (const f16x8*)W;
        f16x8* ldst = (f16x8*)lw;
#pragma unroll
        for (int u = 0; u < 8; ++u) {
            int i = u * 256 + tid;
            ldst[swzv(i)] = gsrc[i];
        }
    }
    // S = sum of the 64 padded slots (one per lane, 64-lane shuffle reduce)
    float sv_ = slots[lane * 16];
#pragma unroll
    for (int o = 1; o < 64; o <<= 1) sv_ += __shfl_xor(sv_, o);
    float invS = 1.0f / sv_;

    __syncthreads();
    if (!active) return;

    f32x4 acc[8];
#pragma unroll
    for (int t = 0; t < 8; ++t) acc[t] = (f32x4){0.f, 0.f, 0.f, 0.f};

    const f16x8* lv = (const f16x8*)lw;
#pragma unroll
    for (int kb = 0; kb < 4; ++kb) {
#pragma unroll
        for (int t = 0; t < 8; ++t) {
            f16x8 b = lv[swzv((t * 16 + r16) * 16 + kb * 4 + quad)];
            acc[t] = __builtin_amdgcn_mfma_f32_16x16x32_f16(a[kb], b, acc[t], 0, 0, 0);
        }
    }
    float sv[4];
#pragma unroll
    for (int i = 0; i < 4; ++i) {
        int r = mb + quad * 4 + i;
        sv[i] = (r < M) ? sexp[r] * invS : 0.f;
    }
#pragma unroll
    for (int t = 0; t < 8; ++t) {
        int col = t * 16 + r16;
        float bv = vb[col];
#pragma unroll
        for (int i = 0; i < 4; ++i) {
            int r = mb + quad * 4 + i;
            if (r < M)
                out[(size_t)r * 128 + col] = (acc[t][i] + bv) * sv[i];
        }
    }
}

// ---- fused attention: one wave per dst, h-only gather; 64-slot S ----------
__global__ __launch_bounds__(256) void attn_fused_h(
    const f16* __restrict__ Qp, const f16* __restrict__ H,
    const float* __restrict__ qc, const int* __restrict__ off,
    const int* __restrict__ lstm, f16* __restrict__ U,
    float* __restrict__ sexp, float* __restrict__ slots, int N)
{
    const int tid  = threadIdx.x;
    const int w    = blockIdx.x * 4 + (tid >> 6);
    const int lane = tid & 63;
    const int sub  = lane >> 4;
    const int c    = lane & 15;
    const float scale = 0.08838834764831845f;  // 1/sqrt(128)

    float acc[8];
#pragma unroll
    for (int j = 0; j < 8; ++j) acc[j] = 0.f;
    float ssum = 0.f;
    float factor = 0.f;

    if (w < N) {
        factor = __expf(qc[w] * scale);
        int b = off[w], e = off[w + 1];
        if (b < e) {
            f16x8 qh = *(const f16x8*)(Qp + (size_t)w * 128 + c * 8);
            f16x2 q2[4];
#pragma unroll
            for (int j = 0; j < 4; ++j) q2[j] = ((const f16x2*)&qh)[j];
            for (int i = b; i < e; i += 16) {
                int m[4]; bool val[4];
#pragma unroll
                for (int u = 0; u < 4; ++u) {
                    int id = i + sub * 4 + u;
                    val[u] = id < e;
                    m[u] = lstm[val[u] ? id : b];
                }
                f16x8 hh[4];
#pragma unroll
                for (int u = 0; u < 4; ++u)
                    hh[u] = *(const f16x8*)(H + (size_t)m[u] * 128 + c * 8);
                float p[4];
#pragma unroll
                for (int u = 0; u < 4; ++u) {
                    float s = 0.f;
                    const f16x2* h2 = (const f16x2*)&hh[u];
#pragma unroll
                    for (int j = 0; j < 4; ++j)
#if __has_builtin(__builtin_amdgcn_fdot2)
                        s = __builtin_amdgcn_fdot2(q2[j], h2[j], s, false);
#else
                        s += (float)q2[j][0] * (float)h2[j][0]
                           + (float)q2[j][1] * (float)h2[j][1];
#endif
                    p[u] = s;
                }
#pragma unroll
                for (int o = 1; o < 16; o <<= 1) {
#pragma unroll
                    for (int u = 0; u < 4; ++u)
                        p[u] += __shfl_xor(p[u], o);
                }
                float a[4];
#pragma unroll
                for (int u = 0; u < 4; ++u)
                    a[u] = val[u] ? __expf(p[u] * scale) : 0.f;
                ssum += (a[0] + a[1]) + (a[2] + a[3]);
#pragma unroll
                for (int u = 0; u < 4; ++u)
#pragma unroll
                    for (int j = 0; j < 8; ++j)
                        acc[j] += a[u] * (float)hh[u][j];
            }
        }
    }
    float stot = ssum;
    stot += __shfl_xor(stot, 16);
    stot += __shfl_xor(stot, 32);

    if (w < N) {
#pragma unroll
        for (int j = 0; j < 8; ++j) {
            acc[j] += __shfl_xor(acc[j], 16);
            acc[j] += __shfl_xor(acc[j], 32);
        }
        if (sub == 0) {
            float inv = (stot > 0.f) ? 1.0f / stot : 0.f;
            f16x8 o;
#pragma unroll
            for (int j = 0; j < 8; ++j) o[j] = (f16)(acc[j] * inv);
            *(f16x8*)(U + (size_t)w * 128 + c * 8) = o;
        }
    }
    float sg = stot * factor;   // 0 for w>=N
    if (lane == 0 && w < N) sexp[w] = sg;
    __shared__ float bs[4];
    if (lane == 0) bs[tid >> 6] = sg;
    __syncthreads();
    if (tid == 0) {
        float t = bs[0] + bs[1] + bs[2] + bs[3];
        if (t != 0.f) atomicAdd(&slots[(blockIdx.x & 63) * 16], t);
    }
}

// ---------------------------------------------------------------------------
extern "C" void kernel_launch(void* const* d_in, const int* in_sizes, int n_in,
                              void* d_out, int out_size, void* d_ws, size_t ws_size,
                              hipStream_t stream)
{
    const float* x_src = (const float*)d_in[0];
    const float* x_mid = (const float*)d_in[1];
    const float* x_dst = (const float*)d_in[2];
    const int*   ei1   = (const int*)d_in[3];
    const int*   ei2   = (const int*)d_in[4];
    const float* W1_w  = (const float*)d_in[5];
    const float* W1_b  = (const float*)d_in[6];
    const float* W2_w  = (const float*)d_in[7];
    const float* W2_b  = (const float*)d_in[8];
    const float* q_w   = (const float*)d_in[9];
    const float* q_b   = (const float*)d_in[10];
    const float* k_w   = (const float*)d_in[11];
    const float* k_b   = (const float*)d_in[12];
    const float* v_w   = (const float*)d_in[13];
    const float* v_b   = (const float*)d_in[14];

    const int NSRC = in_sizes[0] / 128;
    const int NMID = in_sizes[1] / 128;
    const int NDST = in_sizes[2] / 128;
    const int E1   = in_sizes[3] / 2;
    const int E2   = in_sizes[4] / 2;
    const int nb2g = (NDST + 3) / 4;               // attn grid
    const int nb1  = (NMID + 255) >> 8;            // coarse buckets
    const int nb2  = (NDST + 255) >> 8;

    auto al4 = [](size_t n) { return (n + 3) & ~(size_t)3; };

    // ---- workspace layout ----
    f16* xs_h = (f16*)d_ws;                        // NSRC*128
    f16* h_h  = xs_h + (size_t)NSRC * 128;         // NMID*128 (H)
    f16* s_h  = h_h + (size_t)NMID * 128;          // NMID*128
    f16* qp_h = s_h + (size_t)NMID * 128;          // NDST*128 (Q')
    f16* u_h  = qp_h + (size_t)NDST * 128;         // NDST*128 (U^)
    f16* w_h  = u_h + (size_t)NDST * 128;          // 4*16384
    f16* wvh = w_h + 2 * 16384;
    f16* wqk = w_h + 3 * 16384;

    float* b12 = (float*)(w_h + 4 * 16384);        // 128
    float* bqk = b12 + 128;                        // 128
    float* wqkb = bqk + 128;                       // 128
    float* cconst = wqkb + 128;                    // 4
    float* deg = cconst + 4;                       // NMID
    float* qcv = deg + al4(NMID);                  // NDST
    float* sexp = qcv + al4(NDST);                 // NDST
    float* slots = sexp + al4(NDST);               // 64*16 (padded S slots)

    int2* pairs1 = (int2*)(slots + 64 * 16);       // E1  (8B-aligned by layout)
    int2* pairs2 = pairs1 + E1;                    // E2
    int*  cb1   = (int*)(pairs2 + E2);             // nb1+1
    int*  cb2   = cb1 + al4(nb1 + 1);              // nb2+1
    int*  hp1   = cb2 + al4(nb2 + 1);              // NHIST*nb1 (partial hists)
    int*  hp2   = hp1 + NHIST * nb1;               // NHIST*nb2
    int*  cur1p = hp2 + NHIST * nb2;               // nb1*16
    int*  cur2p = cur1p + nb1 * 16;                // nb2*16
    int*  off1  = cur2p + nb2 * 16;                // NMID+1
    int*  off2  = off1 + al4(NMID + 1);            // NDST+1
    int*  lst1  = off2 + al4(NDST + 1);            // E1 (src, grouped by mid)
    int*  lstm2 = lst1 + al4(E1);                  // E2 (mid, grouped by dst)

    // ---- fused setup + partial histogram ----
    {
        int na4 = NSRC * 32;
        int totalA = 4 * 16384 + 257 + na4;
        int NS = (totalA + 255) / 256;
        setup_hist<<<NS + NHIST, 256, 0, stream>>>(
            W1_w, W2_w, v_w, W1_b, W2_b, q_w, k_w, q_b, k_b, x_src,
            w_h, b12, bqk, wqkb, cconst, xs_h, na4, NS,
            ei1 + E1, E1, nb1, hp1,
            ei2 + E2, E2, nb2, hp2);
    }
    coarse_scan<<<1, 256, 0, stream>>>(hp1, nb1, E1, cb1, cur1p,
                                       hp2, nb2, E2, cb2, cur2p, slots);
    {
        int nch1 = (E1 + SP_CHUNK - 1) / SP_CHUNK;
        int nch2 = (E2 + SP_CHUNK - 1) / SP_CHUNK;
        scatter_pairs_blk<<<nch1 + nch2, 256, 0, stream>>>(
            ei1, E1, nb1, cur1p, pairs1, nch1,
            ei2, E2, nb2, cur2p, pairs2);
    }
    bucket_sort<<<nb1 + nb2, 256, 0, stream>>>(
        pairs1, cb1, nb1, NMID, E1, off1, lst1,
        pairs2, cb2, nb2, NDST, E2, off2, lstm2);

    // ---- stage 1 + Q' (separate: LDS-free pull1 keeps full occupancy) ----
    pull1_h<<<(NMID + 3) / 4, 256, 0, stream>>>(xs_h, off1, lst1, s_h, deg, NMID);

    int gbm = ((NMID + 15) / 16 + 3) / 4;
    int gbd = ((NDST + 15) / 16 + 3) / 4;
    gemm_stage1_mfma<<<gbm, 256, 0, stream>>>(x_mid, s_h, w_h /*w1|w2*/, b12,
                                              deg, h_h, NMID);
    gemm_qp_mfma<<<gbd, 256, 0, stream>>>(x_dst, wqk, bqk, wqkb, cconst,
                                          qp_h, qcv, NDST);

    // ---- fused attention (h-gather) + projection/normalize ----
    attn_fused_h<<<nb2g, 256, 0, stream>>>(qp_h, h_h, qcv, off2, lstm2,
                                           u_h, sexp, slots, NDST);
    gemm_v_mfma<<<gbd, 256, 0, stream>>>(u_h, wvh, v_b, sexp, slots,
                                         (float*)d_out, NDST);
}

// Round 13
// 320.910 us; speedup vs baseline: 1.7929x; 1.0131x over previous
//
#include <hip/hip_runtime.h>
#include <cstdint>
#include <cstddef>

// ---------------------------------------------------------------------------
// AtomicRouteConv, sort-based CSR + fp16 MFMA pipeline.
//   R1: scatter occupancy fix (SP_CHUNK 2048, one chunk/list per block).
//   R2: MFMA QK^T in attn -> REGRESSED (latency-bound). Reverted.
//   R3: 16-edge tiles + fdot2 in attn; pull1 16-wide.
//   R4/R5: algebraic K/V elimination; U stored locally-normalized (f16-safe).
//   R6: GEMM weight LDS staging (XOR-swizzled). 344us.
//   R7: CRASHED (fused dual-MFMA s1qp kernel; dropped).
//   R8: single-float atomic-S REGRESSED (one-cache-line serialization).
//   R9: contention-free partial[]+reduce; setup fusion; f32 A-reads. 325.8us.
//   R10: cooperative grid.sync CSR REGRESSED HARD (grid.sync ~70us each).
//   R11: pull1+qp fusion REGRESSED (32KB LDS charged to all blocks).
//   R12: un-fused R9 structure + R11's good parts. 325.1us. setup_hist top
//   at 43us, occ 15%: R11's partial-hist refactor silently cut hist blocks
//   512 -> 64 -> 78 edges/thread serial chain (same disease as R0 scatter).
//   R13: NHIST 64 -> 512 (10 edges/thread; scan sums 512 partials, ~2us).
//   CSR1 (by mid): s[m] = sum x_src rows (f16 gather, f32 acc), deg[m]
//   h = deg*(x_mid@W1^T + b12) + s@W2^T      (MFMA; x_mid read f32)
//   Q' = x_dst@(q_w^T k_w)+q_b k_w (prefused); qc = x_dst.wqkb + qb.kb
//   CSR2 (by dst), one wave per dst: U^ = sum(a*h)/sum(a), sexp = f*sum(a)
//   out = sexp/S * (U^@v_w^T + v_b);  S = 64 padded atomic slots.
// NOTE: bucket = key>>8 requires N <= 65536 (here N=50000).
// ---------------------------------------------------------------------------

using f16   = _Float16;
using f16x2 = __attribute__((ext_vector_type(2))) _Float16;
using f16x4 = __attribute__((ext_vector_type(4))) _Float16;
using f16x8 = __attribute__((ext_vector_type(8))) _Float16;
using f32x4 = __attribute__((ext_vector_type(4))) float;

#define SP_CHUNK 2048
#define NHIST 512

// LDS swizzle on 16B-vector index: XOR row&7 (row = vec>>4) into bits [0:2].
// B-fragment read (r16 strided 256B) 16-way -> 2-way bank conflict (free).
__device__ __forceinline__ int swzv(int v) { return v ^ ((v >> 4) & 7); }

// ---- fused setup + partial histogram --------------------------------------
// Blocks [0, NS): setup (weight cvt + b12 + prefused qk + x_src cvt).
// Blocks [NS, NS+NHIST): LDS-aggregated histogram, block hb WRITES its
// private partial to hp1[hb*nb1+i] / hp2[hb*nb2+i] (no zeroed globals).
__global__ __launch_bounds__(256) void setup_hist(
    const float* __restrict__ W1, const float* __restrict__ W2,
    const float* __restrict__ vw, const float* __restrict__ b1,
    const float* __restrict__ b2, const float* __restrict__ qw,
    const float* __restrict__ kw, const float* __restrict__ qb,
    const float* __restrict__ kb, const float* __restrict__ xsrc,
    f16* __restrict__ wh, float* __restrict__ b12,
    float* __restrict__ bqk, float* __restrict__ wqkb,
    float* __restrict__ cconst, f16* __restrict__ xs_h, int na4, int NS,
    const int* __restrict__ k1, int E1, int nb1, int* __restrict__ hp1,
    const int* __restrict__ k2, int E2, int nb2, int* __restrict__ hp2)
{
    __shared__ int h[512];
    int tid = threadIdx.x;
    if (blockIdx.x < NS) {
        int idx = blockIdx.x * 256 + tid;
        if (idx < 3 * 16384) {
            const float* src = (idx < 16384) ? W1 :
                               (idx < 2 * 16384) ? W2 : vw;
            wh[idx] = (f16)src[idx & 16383];
        } else if (idx < 3 * 16384 + 128) {
            int j = idx - 3 * 16384;
            b12[j] = b1[j] + b2[j];
        } else if (idx < 4 * 16384 + 128) {
            int e = idx - (3 * 16384 + 128);
            int col = e >> 7, i = e & 127;
            float s = 0.f;
            for (int j = 0; j < 128; ++j)
                s += qw[j * 128 + i] * kw[j * 128 + col];
            wh[3 * 16384 + col * 128 + i] = (f16)s;
        } else if (idx < 4 * 16384 + 256) {
            int t = idx - (4 * 16384 + 128);
            float s1 = 0.f, s2 = 0.f;
            for (int j = 0; j < 128; ++j) {
                s1 += qw[j * 128 + t] * kb[j];
                s2 += qb[j] * kw[j * 128 + t];
            }
            wqkb[t] = s1;
            bqk[t] = s2;
        } else if (idx == 4 * 16384 + 256) {
            float s3 = 0.f;
            for (int j = 0; j < 128; ++j) s3 += qb[j] * kb[j];
            cconst[0] = s3;
        } else {
            int j = idx - (4 * 16384 + 257);
            if (j < na4) {
                float4 v = ((const float4*)xsrc)[j];
                f16x4 o = {(f16)v.x, (f16)v.y, (f16)v.z, (f16)v.w};
                ((f16x4*)xs_h)[j] = o;
            }
        }
    } else {
        int hb = blockIdx.x - NS;
        for (int i = tid; i < nb1 + nb2; i += 256) h[i] = 0;
        __syncthreads();
        int stride = NHIST * 256;
        for (int e = hb * 256 + tid; e < E1; e += stride)
            atomicAdd(&h[k1[e] >> 8], 1);
        for (int e = hb * 256 + tid; e < E2; e += stride)
            atomicAdd(&h[nb1 + (k2[e] >> 8)], 1);
        __syncthreads();
        for (int i = tid; i < nb1; i += 256) hp1[hb * nb1 + i] = h[i];
        for (int i = tid; i < nb2; i += 256) hp2[hb * nb2 + i] = h[nb1 + i];
    }
}

// ---- scan: sum partials -> bases + cursors; zero S slots ------------------
__global__ __launch_bounds__(256) void coarse_scan(
    const int* __restrict__ hp1, int nb1, int E1, int* __restrict__ cb1, int* __restrict__ cur1p,
    const int* __restrict__ hp2, int nb2, int E2, int* __restrict__ cb2, int* __restrict__ cur2p,
    float* __restrict__ slots)
{
    __shared__ int sd[256];
    int tid = threadIdx.x;
    int v = 0;
    if (tid < nb1)
        for (int b = 0; b < NHIST; ++b) v += hp1[b * nb1 + tid];
    sd[tid] = v; __syncthreads();
    for (int d = 1; d < 256; d <<= 1) {
        int t = (tid >= d) ? sd[tid - d] : 0;
        __syncthreads(); sd[tid] += t; __syncthreads();
    }
    if (tid < nb1) { int ex = sd[tid] - v; cb1[tid] = ex; cur1p[tid * 16] = ex; }
    if (tid == 0) cb1[nb1] = E1;
    __syncthreads();
    int v2 = 0;
    if (tid < nb2)
        for (int b = 0; b < NHIST; ++b) v2 += hp2[b * nb2 + tid];
    sd[tid] = v2; __syncthreads();
    for (int d = 1; d < 256; d <<= 1) {
        int t = (tid >= d) ? sd[tid - d] : 0;
        __syncthreads(); sd[tid] += t; __syncthreads();
    }
    if (tid < nb2) { int ex = sd[tid] - v2; cb2[tid] = ex; cur2p[tid * 16] = ex; }
    if (tid == 0) cb2[nb2] = E2;
    for (int i = tid; i < 64 * 16; i += 256) slots[i] = 0.f;
}

// ---- CSR build: block-chunked pair scatter --------------------------------
__device__ __forceinline__ void scatter_chunk(
    const int* __restrict__ keys, const int* __restrict__ pay, int E,
    int* __restrict__ curp, int2* __restrict__ out,
    int* hist, int* base, int nbk, int chunk)
{
    int tid = threadIdx.x;
    int start = chunk * SP_CHUNK;
    if (start >= E) return;
    int end = start + SP_CHUNK; if (end > E) end = E;

    for (int i = tid; i < nbk; i += 256) hist[i] = 0;
    __syncthreads();
    for (int i = start + tid; i < end; i += 256)
        atomicAdd(&hist[keys[i] >> 8], 1);
    __syncthreads();
    for (int i = tid; i < nbk; i += 256) {
        int c = hist[i];
        base[i] = c ? atomicAdd(&curp[i * 16], c) : 0;
        hist[i] = 0;   // reuse as local cursor
    }
    __syncthreads();
    for (int i = start + tid; i < end; i += 256) {
        int key = keys[i];
        int b = key >> 8;
        int lp = atomicAdd(&hist[b], 1);
        out[base[b] + lp] = make_int2(key, pay[i]);
    }
}

__global__ __launch_bounds__(256) void scatter_pairs_blk(
    const int* __restrict__ ei1, int E1, int nb1, int* __restrict__ cur1p,
    int2* __restrict__ p1, int nch1,
    const int* __restrict__ ei2, int E2, int nb2, int* __restrict__ cur2p,
    int2* __restrict__ p2)
{
    __shared__ int hist[256];
    __shared__ int base[256];
    int b = blockIdx.x;
    if (b < nch1)
        scatter_chunk(ei1 + E1, ei1, E1, cur1p, p1, hist, base, nb1, b);
    else
        scatter_chunk(ei2 + E2, ei2, E2, cur2p, p2, hist, base, nb2, b - nch1);
}

// ---- CSR build: per-bucket counting sort -> off[] + payload[] -------------
__global__ __launch_bounds__(256) void bucket_sort(
    const int2* __restrict__ p1, const int* __restrict__ cb1, int nb1, int N1, int E1,
    int* __restrict__ off1, int* __restrict__ out1,
    const int2* __restrict__ p2, const int* __restrict__ cb2, int nb2, int N2, int E2,
    int* __restrict__ off2, int* __restrict__ out2)
{
    __shared__ int hist[256];
    __shared__ int scn[256];
    int kb = blockIdx.x;
    const int2* pairs; const int* cb; int N, E; int* offk; int* outp;
    if (kb < nb1) { pairs = p1; cb = cb1; N = N1; E = E1; offk = off1; outp = out1; }
    else { kb -= nb1; pairs = p2; cb = cb2; N = N2; E = E2; offk = off2; outp = out2; }
    int tid = threadIdx.x;
    int base = cb[kb], cnt = cb[kb + 1] - base;
    int key0 = kb << 8;
    int nk = N - key0; if (nk > 256) nk = 256;

    hist[tid] = 0;
    __syncthreads();
    for (int i = tid; i < cnt; i += 256)
        atomicAdd(&hist[pairs[base + i].x - key0], 1);
    __syncthreads();
    int v = hist[tid];
    scn[tid] = v; __syncthreads();
    for (int d = 1; d < 256; d <<= 1) {
        int t = (tid >= d) ? scn[tid - d] : 0;
        __syncthreads(); scn[tid] += t; __syncthreads();
    }
    int ex = scn[tid] - v;
    if (tid < nk) offk[key0 + tid] = base + ex;
    if (tid == 0 && key0 + nk == N) offk[N] = E;
    hist[tid] = ex;   // reuse as per-key cursor
    __syncthreads();
    for (int i = tid; i < cnt; i += 256) {
        int2 pr = pairs[base + i];
        int p = atomicAdd(&hist[pr.x - key0], 1);
        outp[base + p] = pr.y;
    }
}

// ---- pull1: s[m] = sum of fp16 x_src rows; deg[m] (no LDS, max occ) -------
__global__ __launch_bounds__(256) void pull1_h(
    const f16* __restrict__ xs, const int* __restrict__ off,
    const int* __restrict__ lst, f16* __restrict__ s,
    float* __restrict__ deg, int N)
{
    int w = blockIdx.x * 4 + (threadIdx.x >> 6);
    int l = threadIdx.x & 63;
    if (w >= N) return;
    int b = off[w], e = off[w + 1];
    float ax = 0.f, ay = 0.f;
    for (int i = b; i < e; i += 16) {
        int idx[16];
        f16x2 a[16];
#pragma unroll
        for (int u = 0; u < 16; ++u) {
            int id = i + u;
            idx[u] = lst[(id < e) ? id : b];
        }
#pragma unroll
        for (int u = 0; u < 16; ++u)
            a[u] = *(const f16x2*)(xs + (size_t)idx[u] * 128 + l * 2);
#pragma unroll
        for (int u = 0; u < 16; ++u) {
            bool val = (i + u) < e;
            ax += val ? (float)a[u][0] : 0.f;
            ay += val ? (float)a[u][1] : 0.f;
        }
    }
    f16x2 o = {(f16)ax, (f16)ay};
    *(f16x2*)(s + (size_t)w * 128 + l * 2) = o;
    if (l == 0) deg[w] = (float)(e - b);
}

// ---- MFMA Q': Qp = Xd@wqk'^T + bqk; qc = Xd.wqkb + cconst (Xd f32) --------
__global__ __launch_bounds__(256) void gemm_qp_mfma(
    const float* __restrict__ Xd, const f16* __restrict__ W,
    const float* __restrict__ bias, const float* __restrict__ wqkb,
    const float* __restrict__ cconst, f16* __restrict__ Qp,
    float* __restrict__ qc, int M)
{
    __shared__ f16 lw[16384];
    int tid = threadIdx.x;
    int lane = tid & 63;
    int r16 = lane & 15, quad = lane >> 4;
    int gw = (blockIdx.x * 256 + tid) >> 6;
    int mb = gw * 16;
    bool active = mb < M;
    int row = mb + r16; if (row >= M) row = M - 1;

    f32x4 alo[4], ahi[4];
    if (active) {
        const float* xp = Xd + (size_t)row * 128 + quad * 8;
#pragma unroll
        for (int kb = 0; kb < 4; ++kb) {
            alo[kb] = *(const f32x4*)(xp + kb * 32);
            ahi[kb] = *(const f32x4*)(xp + kb * 32 + 4);
        }
    }
    {
        const f16x8* gsrc = (const f16x8*)W;   // 2048 vectors
        f16x8* ldst = (f16x8*)lw;
#pragma unroll
        for (int u = 0; u < 8; ++u) {
            int i = u * 256 + tid;
            ldst[swzv(i)] = gsrc[i];
        }
    }
    __syncthreads();
    if (!active) return;

    f16x8 a[4];
    float pq = 0.f;
#pragma unroll
    for (int kb = 0; kb < 4; ++kb)
#pragma unroll
        for (int j = 0; j < 4; ++j) {
            a[kb][j] = (f16)alo[kb][j];
            a[kb][4 + j] = (f16)ahi[kb][j];
            pq += alo[kb][j] * wqkb[kb * 32 + quad * 8 + j];
            pq += ahi[kb][j] * wqkb[kb * 32 + quad * 8 + 4 + j];
        }

    f32x4 acc[8];
#pragma unroll
    for (int t = 0; t < 8; ++t) acc[t] = (f32x4){0.f, 0.f, 0.f, 0.f};
    const f16x8* lv = (const f16x8*)lw;
#pragma unroll
    for (int kb = 0; kb < 4; ++kb) {
#pragma unroll
        for (int t = 0; t < 8; ++t) {
            f16x8 b = lv[swzv((t * 16 + r16) * 16 + kb * 4 + quad)];
            acc[t] = __builtin_amdgcn_mfma_f32_16x16x32_f16(a[kb], b, acc[t], 0, 0, 0);
        }
    }
    pq += __shfl_xor(pq, 16);
    pq += __shfl_xor(pq, 32);
    if (quad == 0 && mb + r16 < M) qc[mb + r16] = pq + cconst[0];
#pragma unroll
    for (int t = 0; t < 8; ++t) {
        int col = t * 16 + r16;
        float bv = bias[col];
#pragma unroll
        for (int i = 0; i < 4; ++i) {
            int r = mb + quad * 4 + i;
            if (r < M) Qp[(size_t)r * 128 + col] = (f16)(acc[t][i] + bv);
        }
    }
}

// ---- MFMA stage1: H = deg*(Xm@W1^T + b12) + S@W2^T ------------------------
__global__ __launch_bounds__(256) void gemm_stage1_mfma(
    const float* __restrict__ Xm, const f16* __restrict__ S,
    const f16* __restrict__ w12, const float* __restrict__ b12,
    const float* __restrict__ deg, f16* __restrict__ H, int M)
{
    __shared__ f16 lw[32768];   // w1 rows 0-127, w2 rows 128-255 (swizzled)
    int tid = threadIdx.x;
    int lane = tid & 63;
    int r16 = lane & 15, quad = lane >> 4;
    int gw = (blockIdx.x * 256 + tid) >> 6;
    int mb = gw * 16;
    bool active = mb < M;
    int row = mb + r16; if (row >= M) row = M - 1;

    f32x4 alo[4], ahi[4];
    f16x8 a2[4];
    if (active) {
        const float* xa = Xm + (size_t)row * 128 + quad * 8;
        const f16* xb = S + (size_t)row * 128 + quad * 8;
#pragma unroll
        for (int kb = 0; kb < 4; ++kb) {
            alo[kb] = *(const f32x4*)(xa + kb * 32);
            ahi[kb] = *(const f32x4*)(xa + kb * 32 + 4);
            a2[kb] = *(const f16x8*)(xb + kb * 32);
        }
    }
    {
        const f16x8* gsrc = (const f16x8*)w12;   // 4096 16B vectors
        f16x8* ldst = (f16x8*)lw;
#pragma unroll
        for (int u = 0; u < 16; ++u) {
            int i = u * 256 + tid;
            ldst[swzv(i)] = gsrc[i];
        }
    }
    __syncthreads();
    if (!active) return;

    f16x8 a1[4];
#pragma unroll
    for (int kb = 0; kb < 4; ++kb)
#pragma unroll
        for (int j = 0; j < 4; ++j) {
            a1[kb][j] = (f16)alo[kb][j];
            a1[kb][4 + j] = (f16)ahi[kb][j];
        }

    f32x4 accA[8], accB[8];
#pragma unroll
    for (int t = 0; t < 8; ++t) {
        accA[t] = (f32x4){0.f, 0.f, 0.f, 0.f};
        accB[t] = (f32x4){0.f, 0.f, 0.f, 0.f};
    }
    const f16x8* lv = (const f16x8*)lw;
#pragma unroll
    for (int kb = 0; kb < 4; ++kb) {
#pragma unroll
        for (int t = 0; t < 8; ++t) {
            int r = t * 16 + r16;
            f16x8 bw1 = lv[swzv(r * 16 + kb * 4 + quad)];
            f16x8 bw2 = lv[swzv((r + 128) * 16 + kb * 4 + quad)];
            accA[t] = __builtin_amdgcn_mfma_f32_16x16x32_f16(a1[kb], bw1, accA[t], 0, 0, 0);
            accB[t] = __builtin_amdgcn_mfma_f32_16x16x32_f16(a2[kb], bw2, accB[t], 0, 0, 0);
        }
    }
    float dv[4];
#pragma unroll
    for (int i = 0; i < 4; ++i) {
        int r = mb + quad * 4 + i;
        dv[i] = (r < M) ? deg[r] : 0.f;
    }
#pragma unroll
    for (int t = 0; t < 8; ++t) {
        int col = t * 16 + r16;
        float bb = b12[col];
#pragma unroll
        for (int i = 0; i < 4; ++i) {
            int r = mb + quad * 4 + i;
            if (r < M)
                H[(size_t)r * 128 + col] = (f16)(dv[i] * (accA[t][i] + bb) + accB[t][i]);
        }
    }
}

// ---- MFMA V: out = (U^@wv^T + vb) * sexp/S; S = sum of 64 slots -----------
__global__ __launch_bounds__(256) void gemm_v_mfma(
    const f16* U, const f16* __restrict__ W,
    const float* __restrict__ vb, const float* __restrict__ sexp,
    const float* __restrict__ slots, float* __restrict__ out, int M)
{
    __shared__ f16 lw[16384];
    int tid = threadIdx.x;
    int lane = tid & 63;
    int r16 = lane & 15, quad = lane >> 4;
    int gw = (blockIdx.x * 256 + tid) >> 6;
    int mb = gw * 16;
    bool active = mb < M;
    int row = mb + r16; if (row >= M) row = M - 1;

    f16x8 a[4];
    if (active) {
        const f16* xp = U + (size_t)row * 128 + quad * 8;
#pragma unroll
        for (int kb = 0; kb < 4; ++kb)
            a[kb] = *(const f16x8*)(xp + kb * 32);
    }
    {
        const f16x8* gsrc = (const f16x8*)W;
        f16x8* ldst = (f16x8*)lw;
#pragma unroll
        for (int u = 0; u < 8; ++u) {
            int i = u * 256 + tid;
            ldst[swzv(i)] = gsrc[i];
        }
    }
    // S = sum of the 64 padded slots (one per lane, 64-lane shuffle reduce)
    float sv_ = slots[lane * 16];
#pragma unroll
    for (int o = 1; o < 64; o <<= 1) sv_ += __shfl_xor(sv_, o);
    float invS = 1.0f / sv_;

    __syncthreads();
    if (!active) return;

    f32x4 acc[8];
#pragma unroll
    for (int t = 0; t < 8; ++t) acc[t] = (f32x4){0.f, 0.f, 0.f, 0.f};

    const f16x8* lv = (const f16x8*)lw;
#pragma unroll
    for (int kb = 0; kb < 4; ++kb) {
#pragma unroll
        for (int t = 0; t < 8; ++t) {
            f16x8 b = lv[swzv((t * 16 + r16) * 16 + kb * 4 + quad)];
            acc[t] = __builtin_amdgcn_mfma_f32_16x16x32_f16(a[kb], b, acc[t], 0, 0, 0);
        }
    }
    float sv[4];
#pragma unroll
    for (int i = 0; i < 4; ++i) {
        int r = mb + quad * 4 + i;
        sv[i] = (r < M) ? sexp[r] * invS : 0.f;
    }
#pragma unroll
    for (int t = 0; t < 8; ++t) {
        int col = t * 16 + r16;
        float bv = vb[col];
#pragma unroll
        for (int i = 0; i < 4; ++i) {
            int r = mb + quad * 4 + i;
            if (r < M)
                out[(size_t)r * 128 + col] = (acc[t][i] + bv) * sv[i];
        }
    }
}

// ---- fused attention: one wave per dst, h-only gather; 64-slot S ----------
__global__ __launch_bounds__(256) void attn_fused_h(
    const f16* __restrict__ Qp, const f16* __restrict__ H,
    const float* __restrict__ qc, const int* __restrict__ off,
    const int* __restrict__ lstm, f16* __restrict__ U,
    float* __restrict__ sexp, float* __restrict__ slots, int N)
{
    const int tid  = threadIdx.x;
    const int w    = blockIdx.x * 4 + (tid >> 6);
    const int lane = tid & 63;
    const int sub  = lane >> 4;
    const int c    = lane & 15;
    const float scale = 0.08838834764831845f;  // 1/sqrt(128)

    float acc[8];
#pragma unroll
    for (int j = 0; j < 8; ++j) acc[j] = 0.f;
    float ssum = 0.f;
    float factor = 0.f;

    if (w < N) {
        factor = __expf(qc[w] * scale);
        int b = off[w], e = off[w + 1];
        if (b < e) {
            f16x8 qh = *(const f16x8*)(Qp + (size_t)w * 128 + c * 8);
            f16x2 q2[4];
#pragma unroll
            for (int j = 0; j < 4; ++j) q2[j] = ((const f16x2*)&qh)[j];
            for (int i = b; i < e; i += 16) {
                int m[4]; bool val[4];
#pragma unroll
                for (int u = 0; u < 4; ++u) {
                    int id = i + sub * 4 + u;
                    val[u] = id < e;
                    m[u] = lstm[val[u] ? id : b];
                }
                f16x8 hh[4];
#pragma unroll
                for (int u = 0; u < 4; ++u)
                    hh[u] = *(const f16x8*)(H + (size_t)m[u] * 128 + c * 8);
                float p[4];
#pragma unroll
                for (int u = 0; u < 4; ++u) {
                    float s = 0.f;
                    const f16x2* h2 = (const f16x2*)&hh[u];
#pragma unroll
                    for (int j = 0; j < 4; ++j)
#if __has_builtin(__builtin_amdgcn_fdot2)
                        s = __builtin_amdgcn_fdot2(q2[j], h2[j], s, false);
#else
                        s += (float)q2[j][0] * (float)h2[j][0]
                           + (float)q2[j][1] * (float)h2[j][1];
#endif
                    p[u] = s;
                }
#pragma unroll
                for (int o = 1; o < 16; o <<= 1) {
#pragma unroll
                    for (int u = 0; u < 4; ++u)
                        p[u] += __shfl_xor(p[u], o);
                }
                float a[4];
#pragma unroll
                for (int u = 0; u < 4; ++u)
                    a[u] = val[u] ? __expf(p[u] * scale) : 0.f;
                ssum += (a[0] + a[1]) + (a[2] + a[3]);
#pragma unroll
                for (int u = 0; u < 4; ++u)
#pragma unroll
                    for (int j = 0; j < 8; ++j)
                        acc[j] += a[u] * (float)hh[u][j];
            }
        }
    }
    float stot = ssum;
    stot += __shfl_xor(stot, 16);
    stot += __shfl_xor(stot, 32);

    if (w < N) {
#pragma unroll
        for (int j = 0; j < 8; ++j) {
            acc[j] += __shfl_xor(acc[j], 16);
            acc[j] += __shfl_xor(acc[j], 32);
        }
        if (sub == 0) {
            float inv = (stot > 0.f) ? 1.0f / stot : 0.f;
            f16x8 o;
#pragma unroll
            for (int j = 0; j < 8; ++j) o[j] = (f16)(acc[j] * inv);
            *(f16x8*)(U + (size_t)w * 128 + c * 8) = o;
        }
    }
    float sg = stot * factor;   // 0 for w>=N
    if (lane == 0 && w < N) sexp[w] = sg;
    __shared__ float bs[4];
    if (lane == 0) bs[tid >> 6] = sg;
    __syncthreads();
    if (tid == 0) {
        float t = bs[0] + bs[1] + bs[2] + bs[3];
        if (t != 0.f) atomicAdd(&slots[(blockIdx.x & 63) * 16], t);
    }
}

// ---------------------------------------------------------------------------
extern "C" void kernel_launch(void* const* d_in, const int* in_sizes, int n_in,
                              void* d_out, int out_size, void* d_ws, size_t ws_size,
                              hipStream_t stream)
{
    const float* x_src = (const float*)d_in[0];
    const float* x_mid = (const float*)d_in[1];
    const float* x_dst = (const float*)d_in[2];
    const int*   ei1   = (const int*)d_in[3];
    const int*   ei2   = (const int*)d_in[4];
    const float* W1_w  = (const float*)d_in[5];
    const float* W1_b  = (const float*)d_in[6];
    const float* W2_w  = (const float*)d_in[7];
    const float* W2_b  = (const float*)d_in[8];
    const float* q_w   = (const float*)d_in[9];
    const float* q_b   = (const float*)d_in[10];
    const float* k_w   = (const float*)d_in[11];
    const float* k_b   = (const float*)d_in[12];
    const float* v_w   = (const float*)d_in[13];
    const float* v_b   = (const float*)d_in[14];

    const int NSRC = in_sizes[0] / 128;
    const int NMID = in_sizes[1] / 128;
    const int NDST = in_sizes[2] / 128;
    const int E1   = in_sizes[3] / 2;
    const int E2   = in_sizes[4] / 2;
    const int nb2g = (NDST + 3) / 4;               // attn grid
    const int nb1  = (NMID + 255) >> 8;            // coarse buckets
    const int nb2  = (NDST + 255) >> 8;

    auto al4 = [](size_t n) { return (n + 3) & ~(size_t)3; };

    // ---- workspace layout ----
    f16* xs_h = (f16*)d_ws;                        // NSRC*128
    f16* h_h  = xs_h + (size_t)NSRC * 128;         // NMID*128 (H)
    f16* s_h  = h_h + (size_t)NMID * 128;          // NMID*128
    f16* qp_h = s_h + (size_t)NMID * 128;          // NDST*128 (Q')
    f16* u_h  = qp_h + (size_t)NDST * 128;         // NDST*128 (U^)
    f16* w_h  = u_h + (size_t)NDST * 128;          // 4*16384
    f16* wvh = w_h + 2 * 16384;
    f16* wqk = w_h + 3 * 16384;

    float* b12 = (float*)(w_h + 4 * 16384);        // 128
    float* bqk = b12 + 128;                        // 128
    float* wqkb = bqk + 128;                       // 128
    float* cconst = wqkb + 128;                    // 4
    float* deg = cconst + 4;                       // NMID
    float* qcv = deg + al4(NMID);                  // NDST
    float* sexp = qcv + al4(NDST);                 // NDST
    float* slots = sexp + al4(NDST);               // 64*16 (padded S slots)

    int2* pairs1 = (int2*)(slots + 64 * 16);       // E1  (8B-aligned by layout)
    int2* pairs2 = pairs1 + E1;                    // E2
    int*  cb1   = (int*)(pairs2 + E2);             // nb1+1
    int*  cb2   = cb1 + al4(nb1 + 1);              // nb2+1
    int*  hp1   = cb2 + al4(nb2 + 1);              // NHIST*nb1 (partial hists)
    int*  hp2   = hp1 + NHIST * nb1;               // NHIST*nb2
    int*  cur1p = hp2 + NHIST * nb2;               // nb1*16
    int*  cur2p = cur1p + nb1 * 16;                // nb2*16
    int*  off1  = cur2p + nb2 * 16;                // NMID+1
    int*  off2  = off1 + al4(NMID + 1);            // NDST+1
    int*  lst1  = off2 + al4(NDST + 1);            // E1 (src, grouped by mid)
    int*  lstm2 = lst1 + al4(E1);                  // E2 (mid, grouped by dst)

    // ---- fused setup + partial histogram ----
    {
        int na4 = NSRC * 32;
        int totalA = 4 * 16384 + 257 + na4;
        int NS = (totalA + 255) / 256;
        setup_hist<<<NS + NHIST, 256, 0, stream>>>(
            W1_w, W2_w, v_w, W1_b, W2_b, q_w, k_w, q_b, k_b, x_src,
            w_h, b12, bqk, wqkb, cconst, xs_h, na4, NS,
            ei1 + E1, E1, nb1, hp1,
            ei2 + E2, E2, nb2, hp2);
    }
    coarse_scan<<<1, 256, 0, stream>>>(hp1, nb1, E1, cb1, cur1p,
                                       hp2, nb2, E2, cb2, cur2p, slots);
    {
        int nch1 = (E1 + SP_CHUNK - 1) / SP_CHUNK;
        int nch2 = (E2 + SP_CHUNK - 1) / SP_CHUNK;
        scatter_pairs_blk<<<nch1 + nch2, 256, 0, stream>>>(
            ei1, E1, nb1, cur1p, pairs1, nch1,
            ei2, E2, nb2, cur2p, pairs2);
    }
    bucket_sort<<<nb1 + nb2, 256, 0, stream>>>(
        pairs1, cb1, nb1, NMID, E1, off1, lst1,
        pairs2, cb2, nb2, NDST, E2, off2, lstm2);

    // ---- stage 1 + Q' (separate: LDS-free pull1 keeps full occupancy) ----
    pull1_h<<<(NMID + 3) / 4, 256, 0, stream>>>(xs_h, off1, lst1, s_h, deg, NMID);

    int gbm = ((NMID + 15) / 16 + 3) / 4;
    int gbd = ((NDST + 15) / 16 + 3) / 4;
    gemm_stage1_mfma<<<gbm, 256, 0, stream>>>(x_mid, s_h, w_h /*w1|w2*/, b12,
                                              deg, h_h, NMID);
    gemm_qp_mfma<<<gbd, 256, 0, stream>>>(x_dst, wqk, bqk, wqkb, cconst,
                                          qp_h, qcv, NDST);

    // ---- fused attention (h-gather) + projection/normalize ----
    attn_fused_h<<<nb2g, 256, 0, stream>>>(qp_h, h_h, qcv, off2, lstm2,
                                           u_h, sexp, slots, NDST);
    gemm_v_mfma<<<gbd, 256, 0, stream>>>(u_h, wvh, v_b, sexp, slots,
                                         (float*)d_out, NDST);
}